// Round 1
// 2092.918 us; speedup vs baseline: 2.2948x; 2.2948x over previous
//
#include <hip/hip_runtime.h>

#define INV_SQRT_2 0.70710678118654752440f
#define INV_SQRT_3 0.57735026918962576451f

typedef __bf16 bf16_t;
typedef __bf16 bf16x8 __attribute__((ext_vector_type(8)));
typedef float f32x4 __attribute__((ext_vector_type(4)));

__device__ __forceinline__ float toF(float x) { return x; }
__device__ __forceinline__ float toF(bf16_t x) { return (float)x; }
__device__ __forceinline__ float siluf(float x) { return x / (1.f + __expf(-x)); }

template <typename T> __device__ __forceinline__ T fromF(float x);
template <> __device__ __forceinline__ float fromF<float>(float x) { return x; }
template <> __device__ __forceinline__ bf16_t fromF<bf16_t>(float x) { return (bf16_t)x; }

__device__ __forceinline__ bf16x8 ld8(const bf16_t* p) { return *(const bf16x8*)p; }
__device__ __forceinline__ bf16x8 ld8(const float* p) {
  bf16x8 r;
#pragma unroll
  for (int j = 0; j < 8; ++j) r[j] = (bf16_t)p[j];
  return r;
}

__device__ __forceinline__ f32x4 MFMA(bf16x8 a, bf16x8 b, f32x4 c) {
  return __builtin_amdgcn_mfma_f32_16x16x32_bf16(a, b, c, 0, 0, 0);
}

// Packed-B fragment: element j of lane l = B[ks*32 + (l>>4)*8 + j][nt*16 + (l&15)]
__device__ __forceinline__ bf16x8 ldB(const bf16_t* Bp, int ks, int nt, int NT, int lane) {
  return *(const bf16x8*)(Bp + ((((size_t)ks * NT + nt) * 64 + lane) << 3));
}

// hi/lo split accumulate: each matrix packed as [hi(SZ) | lo(SZ)].
// WS=true (f32 input path): W = hi + lo keeps near-f32 weight precision.
template <bool WS, int SZ>
__device__ __forceinline__ f32x4 mfma2(bf16x8 a, const bf16_t* Bp, int ks, int nt, int NT,
                                       int lane, f32x4 c) {
  c = MFMA(a, ldB(Bp, ks, nt, NT, lane), c);
  if (WS) c = MFMA(a, ldB(Bp + SZ, ks, nt, NT, lane), c);
  return c;
}

// ---- dtype detector: probe rbf_h (uniform [0,1]) interpreted as bf16 words.
__global__ void k_detect(const unsigned short* __restrict__ probe, int* __restrict__ flag) {
  __shared__ int cnt;
  if (threadIdx.x == 0) cnt = 0;
  __syncthreads();
  int bad = 0;
  for (int i = threadIdx.x; i < 256; i += 64) {
    unsigned int u = (unsigned int)probe[i] << 16;
    float v = __uint_as_float(u);
    if (!(v == v) || fabsf(v) > 4.f || v < -0.25f) bad++;
  }
  atomicAdd(&cnt, bad);
  __syncthreads();
  if (threadIdx.x == 0) *flag = (cnt > 16) ? 1 : 0;
}

__global__ void k_zero(float* __restrict__ p, int n) {
  int i = blockIdx.x * blockDim.x + threadIdx.x;
  if (i < n) p[i] = 0.f;
}

#define GUARD if (*flag != want) return;

// ---------------- weight repack: W(KxN) -> fragment-linear [hi|lo] ----------------
struct RDesc { const void* src; int K, N, Kpad, dstoff; };
struct RTable { RDesc d[23]; };

template <typename TIN>
__global__ void k_repack(const int* __restrict__ flag, int want, RTable tab,
                         bf16_t* __restrict__ out) {
  GUARD
  RDesc d = tab.d[blockIdx.y];
  int p = blockIdx.x * 256 + threadIdx.x;
  int sz = d.Kpad * d.N;
  if (p >= sz) return;
  int NT = d.N >> 4;
  int j = p & 7;
  int lane = (p >> 3) & 63;
  int q = p >> 9;
  int nt = q % NT, ks = q / NT;
  int k = ks * 32 + ((lane >> 4) << 3) + j;
  int col = nt * 16 + (lane & 15);
  float v = (k < d.K) ? toF(((const TIN*)d.src)[(size_t)k * d.N + col]) : 0.f;
  bf16_t hi = (bf16_t)v;
  out[d.dstoff + p] = hi;
  out[d.dstoff + sz + p] = (bf16_t)(v - (float)hi);
}

// ---------------- plain GEMM + silu: out(bf16, M x NT*16) = silu(A @ W) ----------------
template <typename TA, int NT, int KSTEPS, bool WS>
__global__ __launch_bounds__(256) void k_gemm_mf(const int* __restrict__ flag, int want,
    const TA* __restrict__ A, const bf16_t* __restrict__ Bp, bf16_t* __restrict__ out, int M) {
  GUARD
  const int lane = threadIdx.x & 63, wid = threadIdx.x >> 6;
  const int row0 = (blockIdx.x * 4 + wid) << 4;
  if (row0 >= M) return;
  const int rc = lane & 15, g = lane >> 4;
  const int K = KSTEPS * 32;
  const TA* ap = A + (size_t)(row0 + rc) * K;
  f32x4 acc[NT] = {};
#pragma unroll
  for (int ks = 0; ks < KSTEPS; ++ks) {
    bf16x8 a = ld8(ap + ks * 32 + g * 8);
#pragma unroll
    for (int nt = 0; nt < NT; ++nt)
      acc[nt] = mfma2<WS, KSTEPS * 32 * NT * 16>(a, Bp, ks, nt, NT, lane, acc[nt]);
  }
  const int Nc = NT * 16;
  bf16_t* op = out + (size_t)(row0 + g * 4) * Nc + rc;
#pragma unroll
  for (int nt = 0; nt < NT; ++nt)
#pragma unroll
    for (int r = 0; r < 4; ++r) op[(size_t)r * Nc + nt * 16] = (bf16_t)siluf(acc[nt][r]);
}

// ---- m_kt pre: out = silu(m_st @ Wt_mkt) * (rbf3 @ Wt_rbf), K_gate=16 zero-padded to 32 ----
template <typename TIN, bool WS>
__global__ __launch_bounds__(256) void k_mkt_mf(const int* __restrict__ flag, int want,
    const TIN* __restrict__ mst, const TIN* __restrict__ rbf3,
    const bf16_t* __restrict__ Wm, const bf16_t* __restrict__ Wr,
    bf16_t* __restrict__ out, int M) {
  GUARD
  const int lane = threadIdx.x & 63, wid = threadIdx.x >> 6;
  const int row0 = (blockIdx.x * 4 + wid) << 4;
  if (row0 >= M) return;
  const int rc = lane & 15, g = lane >> 4;
  const TIN* ap = mst + (size_t)(row0 + rc) * 128;
  f32x4 am[8] = {}, ag[8] = {};
#pragma unroll
  for (int ks = 0; ks < 4; ++ks) {
    bf16x8 a = ld8(ap + ks * 32 + g * 8);
#pragma unroll
    for (int nt = 0; nt < 8; ++nt) am[nt] = mfma2<WS, 16384>(a, Wm, ks, nt, 8, lane, am[nt]);
  }
  bf16x8 az = {};
  if (g < 2) az = ld8(rbf3 + (size_t)(row0 + rc) * 16 + g * 8);
#pragma unroll
  for (int nt = 0; nt < 8; ++nt) ag[nt] = mfma2<WS, 4096>(az, Wr, 0, nt, 8, lane, ag[nt]);
  bf16_t* op = out + (size_t)(row0 + g * 4) * 128 + rc;
#pragma unroll
  for (int nt = 0; nt < 8; ++nt)
#pragma unroll
    for (int r = 0; r < 4; ++r)
      op[(size_t)r * 128 + nt * 16] = (bf16_t)(siluf(am[nt][r]) * ag[nt][r]);
}

// ---- efficient bilinear (unchanged scalar version): one edge per 64-thread block ----
template <typename TIN>
__global__ void k_bilinear_b(const int* __restrict__ flag, int want,
                             const TIN* __restrict__ basis, const bf16_t* __restrict__ msrc,
                             const int* __restrict__ gidx, const TIN* __restrict__ W,
                             bf16_t* __restrict__ out) {
  GUARD
  int e = blockIdx.x;
  int tid = threadIdx.x;
  __shared__ float sumk[16 * 64];
#pragma unroll
  for (int b = 0; b < 16; ++b) sumk[b * 64 + tid] = 0.f;
  __syncthreads();
  for (int k = 0; k < 6; ++k) {
    int t = e * 6 + k;
    int row = gidx[t];
    float mi = (float)msrc[(size_t)row * 64 + tid];
    const TIN* bs = basis + (size_t)t * 16;
#pragma unroll
    for (int b = 0; b < 16; ++b) sumk[b * 64 + tid] += toF(bs[b]) * mi;
  }
  __syncthreads();
  float acc = 0.f;
  for (int i = 0; i < 64; ++i) {
#pragma unroll
    for (int b = 0; b < 16; ++b) acc += sumk[b * 64 + i] * toF(W[i * 1024 + b * 64 + tid]);
  }
  out[(size_t)e * 64 + tid] = (bf16_t)acc;
}

// ---- fused combine (5 GEMM groups, swap-gather on A-fragment rows) -> X ----
// X = x_skip*r3 + (silu(xt@Wst)+silu(xt[s]@Wts))*r2*r3 + (silu(xq@Wst)+silu(xq[s]@Wts))*r2*r3
template <typename TIN, bool WS>
__global__ __launch_bounds__(256) void k_comb_mf(const int* __restrict__ flag, int want,
    const TIN* __restrict__ mst, const bf16_t* __restrict__ xt, const bf16_t* __restrict__ xq,
    const int* __restrict__ idx_swap,
    const bf16_t* Wsk, const bf16_t* Wtst, const bf16_t* Wtts,
    const bf16_t* Wqst, const bf16_t* Wqts,
    bf16_t* __restrict__ X, int M) {
  GUARD
  const int lane = threadIdx.x & 63, wid = threadIdx.x >> 6;
  const int row0 = (blockIdx.x * 4 + wid) << 4;
  if (row0 >= M) return;
  const int rc = lane & 15, g = lane >> 4;
  const int arow = row0 + rc;
  const int srow = idx_swap[arow];
  const int nb = blockIdx.y * 4;  // column-half: nt in [nb, nb+4)
  f32x4 aV[4] = {}, a3[4] = {}, b3[4] = {}, a4[4] = {}, b4[4] = {};
#pragma unroll
  for (int ks = 0; ks < 4; ++ks) {
    bf16x8 a = ld8(mst + (size_t)arow * 128 + ks * 32 + g * 8);
#pragma unroll
    for (int t = 0; t < 4; ++t) aV[t] = mfma2<WS, 16384>(a, Wsk, ks, nb + t, 8, lane, aV[t]);
  }
#pragma unroll
  for (int ks = 0; ks < 2; ++ks) {
    bf16x8 a = ld8(xt + (size_t)arow * 64 + ks * 32 + g * 8);
#pragma unroll
    for (int t = 0; t < 4; ++t) a3[t] = mfma2<WS, 8192>(a, Wtst, ks, nb + t, 8, lane, a3[t]);
  }
#pragma unroll
  for (int ks = 0; ks < 2; ++ks) {
    bf16x8 a = ld8(xt + (size_t)srow * 64 + ks * 32 + g * 8);
#pragma unroll
    for (int t = 0; t < 4; ++t) b3[t] = mfma2<WS, 8192>(a, Wtts, ks, nb + t, 8, lane, b3[t]);
  }
#pragma unroll
  for (int ks = 0; ks < 2; ++ks) {
    bf16x8 a = ld8(xq + (size_t)arow * 64 + ks * 32 + g * 8);
#pragma unroll
    for (int t = 0; t < 4; ++t) a4[t] = mfma2<WS, 8192>(a, Wqst, ks, nb + t, 8, lane, a4[t]);
  }
#pragma unroll
  for (int ks = 0; ks < 2; ++ks) {
    bf16x8 a = ld8(xq + (size_t)srow * 64 + ks * 32 + g * 8);
#pragma unroll
    for (int t = 0; t < 4; ++t) b4[t] = mfma2<WS, 8192>(a, Wqts, ks, nb + t, 8, lane, b4[t]);
  }
  bf16_t* op = X + (size_t)(row0 + g * 4) * 128 + rc;
#pragma unroll
  for (int t = 0; t < 4; ++t)
#pragma unroll
    for (int r = 0; r < 4; ++r) {
      float v = aV[t][r] * INV_SQRT_3 +
                (siluf(a3[t][r]) + siluf(b3[t][r])) * (INV_SQRT_2 * INV_SQRT_3) +
                (siluf(a4[t][r]) + siluf(b4[t][r])) * (INV_SQRT_2 * INV_SQRT_3);
      op[(size_t)r * 128 + (nb + t) * 16] = (bf16_t)v;
    }
}

// ---- one residual layer on a wave's 16-row LDS slab: x = (x + silu(silu(x@W0)@W1))*r2 ----
// LDS row stride 136 elems (272B): effectively conflict-free ds_read_b128 fragments.
template <bool WS>
__device__ __forceinline__ void res_layer(bf16_t* Xs, bf16_t* Ys, const bf16_t* W0,
                                          const bf16_t* W1, int wrow0, int lane) {
  const int rc = lane & 15, g = lane >> 4;
  f32x4 acc[8] = {};
#pragma unroll
  for (int ks = 0; ks < 4; ++ks) {
    bf16x8 a = *(const bf16x8*)&Xs[(wrow0 + rc) * 136 + ks * 32 + g * 8];
#pragma unroll
    for (int nt = 0; nt < 8; ++nt) acc[nt] = mfma2<WS, 16384>(a, W0, ks, nt, 8, lane, acc[nt]);
  }
#pragma unroll
  for (int nt = 0; nt < 8; ++nt)
#pragma unroll
    for (int r = 0; r < 4; ++r)
      Ys[(wrow0 + g * 4 + r) * 136 + nt * 16 + rc] = (bf16_t)siluf(acc[nt][r]);
  f32x4 a2[8] = {};
#pragma unroll
  for (int ks = 0; ks < 4; ++ks) {
    bf16x8 a = *(const bf16x8*)&Ys[(wrow0 + rc) * 136 + ks * 32 + g * 8];
#pragma unroll
    for (int nt = 0; nt < 8; ++nt) a2[nt] = mfma2<WS, 16384>(a, W1, ks, nt, 8, lane, a2[nt]);
  }
#pragma unroll
  for (int nt = 0; nt < 8; ++nt)
#pragma unroll
    for (int r = 0; r < 4; ++r) {
      int ix = (wrow0 + g * 4 + r) * 136 + nt * 16 + rc;
      Xs[ix] = (bf16_t)(((float)Xs[ix] + siluf(a2[nt][r])) * INV_SQRT_2);
    }
}

// ---- fused: x=res_before(X); m=(m_st+x)*r2; m=res_after(m) -> out ----
template <typename TIN, bool WS>
__global__ __launch_bounds__(256) void k_resE(const int* __restrict__ flag, int want,
    const bf16_t* __restrict__ Xg, const TIN* __restrict__ mst,
    const bf16_t* W0b, const bf16_t* W1b,
    const bf16_t* W0a, const bf16_t* W1a, const bf16_t* W2a, const bf16_t* W3a,
    bf16_t* __restrict__ outg, int M) {
  GUARD
  __shared__ __align__(16) bf16_t Xs[64 * 136];
  __shared__ __align__(16) bf16_t Ys[64 * 136];
  const int lane = threadIdx.x & 63, wid = threadIdx.x >> 6;
  const int grow0 = blockIdx.x * 64 + wid * 16;
  if (grow0 >= M) return;
  const int wrow0 = wid * 16;
#pragma unroll
  for (int i = 0; i < 4; ++i) {
    int o = i * 512 + lane * 8, r = o >> 7, c = o & 127;
    *(bf16x8*)&Xs[(wrow0 + r) * 136 + c] = *(const bf16x8*)&Xg[(size_t)(grow0 + r) * 128 + c];
  }
  res_layer<WS>(Xs, Ys, W0b, W1b, wrow0, lane);
#pragma unroll
  for (int i = 0; i < 4; ++i) {
    int o = i * 512 + lane * 8, r = o >> 7, c = o & 127;
    const TIN* mp = mst + (size_t)(grow0 + r) * 128 + c;
    bf16_t* xp = &Xs[(wrow0 + r) * 136 + c];
#pragma unroll
    for (int j = 0; j < 8; ++j) xp[j] = (bf16_t)((toF(mp[j]) + (float)xp[j]) * INV_SQRT_2);
  }
  res_layer<WS>(Xs, Ys, W0a, W1a, wrow0, lane);
  res_layer<WS>(Xs, Ys, W2a, W3a, wrow0, lane);
#pragma unroll
  for (int i = 0; i < 4; ++i) {
    int o = i * 512 + lane * 8, r = o >> 7, c = o & 127;
    *(bf16x8*)&outg[(size_t)(grow0 + r) * 128 + c] = *(const bf16x8*)&Xs[(wrow0 + r) * 136 + c];
  }
}

// ---- 2-layer residual stack, in place ----
template <bool WS>
__global__ __launch_bounds__(256) void k_resN(const int* __restrict__ flag, int want,
    bf16_t* __restrict__ Xg, const bf16_t* W0, const bf16_t* W1, const bf16_t* W2,
    const bf16_t* W3, int M) {
  GUARD
  __shared__ __align__(16) bf16_t Xs[64 * 136];
  __shared__ __align__(16) bf16_t Ys[64 * 136];
  const int lane = threadIdx.x & 63, wid = threadIdx.x >> 6;
  const int grow0 = blockIdx.x * 64 + wid * 16;
  if (grow0 >= M) return;
  const int wrow0 = wid * 16;
#pragma unroll
  for (int i = 0; i < 4; ++i) {
    int o = i * 512 + lane * 8, r = o >> 7, c = o & 127;
    *(bf16x8*)&Xs[(wrow0 + r) * 136 + c] = *(const bf16x8*)&Xg[(size_t)(grow0 + r) * 128 + c];
  }
  res_layer<WS>(Xs, Ys, W0, W1, wrow0, lane);
  res_layer<WS>(Xs, Ys, W2, W3, wrow0, lane);
#pragma unroll
  for (int i = 0; i < 4; ++i) {
    int o = i * 512 + lane * 8, r = o >> 7, c = o & 127;
    *(bf16x8*)&Xg[(size_t)(grow0 + r) * 128 + c] = *(const bf16x8*)&Xs[(wrow0 + r) * 136 + c];
  }
}

// ---- atom embedding scatter (unchanged) ----
template <typename TIN>
__global__ void k_scatter(const int* __restrict__ flag, int want,
                          const bf16_t* __restrict__ m, const TIN* __restrict__ rbf_h,
                          const TIN* __restrict__ Wrbf, const int* __restrict__ idx_t,
                          float* __restrict__ h2) {
  GUARD
  int e = blockIdx.x;
  int c = threadIdx.x;
  float g = 0.f;
#pragma unroll
  for (int k = 0; k < 16; ++k) g += toF(rbf_h[(size_t)e * 16 + k]) * toF(Wrbf[k * 128 + c]);
  atomicAdd(&h2[(size_t)idx_t[e] * 128 + c], (float)m[(size_t)e * 128 + c] * g);
}

// ---- h_new = (h + X)*r2 -> out (TOUT) and X (bf16, for ASI) ----
template <typename TIN, typename TOUT>
__global__ void k_hnew_b(const int* __restrict__ flag, int want,
                         const TIN* __restrict__ h, bf16_t* __restrict__ X,
                         TOUT* __restrict__ out, int n) {
  GUARD
  int i = blockIdx.x * blockDim.x + threadIdx.x;
  if (i >= n) return;
  float v = (toF(h[i]) + (float)X[i]) * INV_SQRT_2;
  X[i] = (bf16_t)v;
  out[i] = fromF<TOUT>(v);
}

// ---- fused ASI + res_m + final combine:
// m2 = silu(concat[h_new[s], h_new[t], m] @ W_asi) (gathered A-fragment rows, K=384)
// v = (m2 + silu(silu(m2@Wm0)@Wm1))*r2 ; out_m = (m + v)*r2
template <typename TIN, typename TOUT, bool WS>
__global__ __launch_bounds__(256) void k_asi_res(const int* __restrict__ flag, int want,
    const bf16_t* __restrict__ hnew, const bf16_t* __restrict__ m,
    const int* __restrict__ idx_s, const int* __restrict__ idx_t,
    const bf16_t* Wasi, const bf16_t* Wm0, const bf16_t* Wm1,
    TOUT* __restrict__ outm, int M) {
  GUARD
  __shared__ __align__(16) bf16_t Xs[64 * 136];
  __shared__ __align__(16) bf16_t Ys[64 * 136];
  const int lane = threadIdx.x & 63, wid = threadIdx.x >> 6;
  const int grow0 = blockIdx.x * 64 + wid * 16;
  if (grow0 >= M) return;
  const int wrow0 = wid * 16;
  const int rc = lane & 15, g = lane >> 4;
  const int e = grow0 + rc;
  const int rs = idx_s[e], rt = idx_t[e];
  f32x4 acc[8] = {};
#pragma unroll
  for (int ks = 0; ks < 12; ++ks) {
    const bf16_t* src = (ks < 4) ? hnew + (size_t)rs * 128
                       : (ks < 8) ? hnew + (size_t)rt * 128
                                  : m + (size_t)e * 128;
    bf16x8 a = ld8(src + (ks & 3) * 32 + g * 8);
#pragma unroll
    for (int nt = 0; nt < 8; ++nt) acc[nt] = mfma2<WS, 49152>(a, Wasi, ks, nt, 8, lane, acc[nt]);
  }
#pragma unroll
  for (int nt = 0; nt < 8; ++nt)
#pragma unroll
    for (int r = 0; r < 4; ++r)
      Xs[(wrow0 + g * 4 + r) * 136 + nt * 16 + rc] = (bf16_t)siluf(acc[nt][r]);
  // res_m layer, fused with final (m + v)*r2
  f32x4 a1[8] = {};
#pragma unroll
  for (int ks = 0; ks < 4; ++ks) {
    bf16x8 a = *(const bf16x8*)&Xs[(wrow0 + rc) * 136 + ks * 32 + g * 8];
#pragma unroll
    for (int nt = 0; nt < 8; ++nt) a1[nt] = mfma2<WS, 16384>(a, Wm0, ks, nt, 8, lane, a1[nt]);
  }
#pragma unroll
  for (int nt = 0; nt < 8; ++nt)
#pragma unroll
    for (int r = 0; r < 4; ++r)
      Ys[(wrow0 + g * 4 + r) * 136 + nt * 16 + rc] = (bf16_t)siluf(a1[nt][r]);
  f32x4 a2[8] = {};
#pragma unroll
  for (int ks = 0; ks < 4; ++ks) {
    bf16x8 a = *(const bf16x8*)&Ys[(wrow0 + rc) * 136 + ks * 32 + g * 8];
#pragma unroll
    for (int nt = 0; nt < 8; ++nt) a2[nt] = mfma2<WS, 16384>(a, Wm1, ks, nt, 8, lane, a2[nt]);
  }
#pragma unroll
  for (int nt = 0; nt < 8; ++nt)
#pragma unroll
    for (int r = 0; r < 4; ++r) {
      int row = grow0 + g * 4 + r, col = nt * 16 + rc;
      float x = (float)Xs[(wrow0 + g * 4 + r) * 136 + col];
      float v = (x + siluf(a2[nt][r])) * INV_SQRT_2;
      outm[(size_t)row * 128 + col] = fromF<TOUT>(((float)m[(size_t)row * 128 + col] + v) * INV_SQRT_2);
    }
}

// ================================================================================
template <typename TIN, typename TOUT, bool WS>
static void run_pipeline(void* const* d_in, int N, int E, void* d_out,
                         bf16_t* Wpack, bf16_t* s0, bf16_t* s1, bf16_t* s2, bf16_t* s3,
                         float* h2, bf16_t* Rn2, const int* flag, int want, hipStream_t stream) {
  const TIN* h      = (const TIN*)d_in[0];
  const TIN* m_st   = (const TIN*)d_in[1];
  const TIN* rbf_h  = (const TIN*)d_in[2];
  const TIN* rbf3   = (const TIN*)d_in[3];
  const TIN* cbf3   = (const TIN*)d_in[4];
  const TIN* sbf4   = (const TIN*)d_in[5];
  const int* idx_s   = (const int*)d_in[6];
  const int* idx_t   = (const int*)d_in[7];
  const int* idx_sw  = (const int*)d_in[8];
  const int* id3_kt  = (const int*)d_in[9];
  const int* enb_idx = (const int*)d_in[12];
  const TIN* W_skip   = (const TIN*)d_in[16];
  const TIN* Wt_mkt   = (const TIN*)d_in[17];
  const TIN* Wt_rbf   = (const TIN*)d_in[18];
  const TIN* Wt_down  = (const TIN*)d_in[19];
  const TIN* Wt_cbf   = (const TIN*)d_in[20];
  const TIN* Wt_up_st = (const TIN*)d_in[21];
  const TIN* Wt_up_ts = (const TIN*)d_in[22];
  const TIN* Wq_down  = (const TIN*)d_in[23];
  const TIN* Wq_sbf   = (const TIN*)d_in[24];
  const TIN* Wq_up_st = (const TIN*)d_in[25];
  const TIN* Wq_up_ts = (const TIN*)d_in[26];
  const TIN* Wres_before = (const TIN*)d_in[27];
  const TIN* Wres_after  = (const TIN*)d_in[28];
  const TIN* Wres_m      = (const TIN*)d_in[29];
  const TIN* W_ae_rbf    = (const TIN*)d_in[30];
  const TIN* W_ae_dense  = (const TIN*)d_in[31];
  const TIN* W_ae_res    = (const TIN*)d_in[32];
  const TIN* W_asi       = (const TIN*)d_in[33];

  RTable tab;
  int cur = 0, nd = 0;
  auto add = [&](const void* src, int K, int Np, int Kpad) {
    tab.d[nd].src = src; tab.d[nd].K = K; tab.d[nd].N = Np; tab.d[nd].Kpad = Kpad;
    tab.d[nd].dstoff = cur;
    int o = cur;
    cur += 2 * Kpad * Np;  // hi + lo
    ++nd;
    return o;
  };
  const int M128 = 128 * 128;
  int oQd  = add(Wq_down, 128, 64, 128);
  int oMkt = add(Wt_mkt, 128, 128, 128);
  int oRbf = add(Wt_rbf, 16, 128, 32);      // K=16 zero-padded to 32
  int oTd  = add(Wt_down, 128, 64, 128);
  int oTst = add(Wt_up_st, 64, 128, 64);
  int oTts = add(Wt_up_ts, 64, 128, 64);
  int oQst = add(Wq_up_st, 64, 128, 64);
  int oQts = add(Wq_up_ts, 64, 128, 64);
  int oSk  = add(W_skip, 128, 128, 128);
  int oB0  = add(Wres_before, 128, 128, 128);
  int oB1  = add(Wres_before + M128, 128, 128, 128);
  int oA0  = add(Wres_after, 128, 128, 128);
  int oA1  = add(Wres_after + M128, 128, 128, 128);
  int oA2  = add(Wres_after + 2 * M128, 128, 128, 128);
  int oA3  = add(Wres_after + 3 * M128, 128, 128, 128);
  int oM0  = add(Wres_m, 128, 128, 128);
  int oM1  = add(Wres_m + M128, 128, 128, 128);
  int oAed = add(W_ae_dense, 128, 128, 128);
  int oAe0 = add(W_ae_res, 128, 128, 128);
  int oAe1 = add(W_ae_res + M128, 128, 128, 128);
  int oAe2 = add(W_ae_res + 2 * M128, 128, 128, 128);
  int oAe3 = add(W_ae_res + 3 * M128, 128, 128, 128);
  int oAsi = add(W_asi, 384, 128, 384);
  (void)cur;

  const int gE = E / 64;   // 1250
  const int gN = N / 64;   // 125
  const int BS = 256;

  // workspace overlays (U = E*64 bf16):
  bf16_t* mkt_tmp = s0;  // spans s0+s1 (E x 128)
  bf16_t* m_kt = s2;
  bf16_t* m_d  = s3;
  bf16_t* xt = s0;
  bf16_t* xq = s1;
  bf16_t* X  = s2;       // spans s2+s3 (E x 128)
  bf16_t* R2 = s0;       // spans s0+s1 (E x 128) -- "m" after res stack

  k_repack<TIN><<<dim3(192, 23), BS, 0, stream>>>(flag, want, tab, Wpack);

  k_mkt_mf<TIN, WS><<<gE, BS, 0, stream>>>(flag, want, m_st, rbf3, Wpack + oMkt, Wpack + oRbf,
                                           mkt_tmp, E);
  k_gemm_mf<bf16_t, 4, 4, WS><<<gE, BS, 0, stream>>>(flag, want, mkt_tmp, Wpack + oTd, m_kt, E);
  k_gemm_mf<TIN, 4, 4, WS><<<gE, BS, 0, stream>>>(flag, want, m_st, Wpack + oQd, m_d, E);
  k_bilinear_b<TIN><<<E, 64, 0, stream>>>(flag, want, cbf3, m_kt, id3_kt, Wt_cbf, xt);
  k_bilinear_b<TIN><<<E, 64, 0, stream>>>(flag, want, sbf4, m_d, enb_idx, Wq_sbf, xq);
  k_comb_mf<TIN, WS><<<dim3(gE, 2), BS, 0, stream>>>(flag, want, m_st, xt, xq, idx_sw,
      Wpack + oSk, Wpack + oTst, Wpack + oTts, Wpack + oQst, Wpack + oQts, X, E);
  k_resE<TIN, WS><<<gE, BS, 0, stream>>>(flag, want, X, m_st,
      Wpack + oB0, Wpack + oB1, Wpack + oA0, Wpack + oA1, Wpack + oA2, Wpack + oA3, R2, E);
  // h2 overlays the (now dead) X region; zero then scatter
  k_zero<<<(N * 128 + BS - 1) / BS, BS, 0, stream>>>(h2, N * 128);
  k_scatter<TIN><<<E, 128, 0, stream>>>(flag, want, R2, rbf_h, W_ae_rbf, idx_t, h2);
  k_gemm_mf<float, 8, 4, WS><<<gN, BS, 0, stream>>>(flag, want, h2, Wpack + oAed, Rn2, N);
  k_resN<WS><<<gN, BS, 0, stream>>>(flag, want, Rn2, Wpack + oAe0, Wpack + oAe1,
                                    Wpack + oAe2, Wpack + oAe3, N);
  TOUT* out_h = (TOUT*)d_out;
  TOUT* out_m = out_h + (size_t)N * 128;
  k_hnew_b<TIN, TOUT><<<(N * 128 + BS - 1) / BS, BS, 0, stream>>>(flag, want, h, Rn2, out_h,
                                                                  N * 128);
  k_asi_res<TIN, TOUT, WS><<<gE, BS, 0, stream>>>(flag, want, Rn2, R2, idx_s, idx_t,
      Wpack + oAsi, Wpack + oM0, Wpack + oM1, out_m, E);
}

extern "C" void kernel_launch(void* const* d_in, const int* in_sizes, int n_in,
                              void* d_out, int out_size, void* d_ws, size_t ws_size,
                              hipStream_t stream) {
  const int D = 128;
  const int N = in_sizes[0] / D;   // 8000
  const int E = in_sizes[1] / D;   // 80000

  // workspace: Wpack (2*348160 bf16 = 1,392,640 B) | flag | 4 slots of E*64 bf16 (~41 MB)
  char* base = (char*)d_ws;
  bf16_t* Wpack = (bf16_t*)base;
  int* flag = (int*)(base + 1392640);
  char* dyn = base + 1392896;
  size_t U = (size_t)E * 64 * sizeof(bf16_t);
  bf16_t* s0 = (bf16_t*)dyn;
  bf16_t* s1 = (bf16_t*)(dyn + U);
  bf16_t* s2 = (bf16_t*)(dyn + 2 * U);
  bf16_t* s3 = (bf16_t*)(dyn + 3 * U);
  float* h2 = (float*)(dyn + 2 * U);                              // reuses X region (dead by then)
  bf16_t* Rn2 = (bf16_t*)((char*)h2 + (size_t)N * 128 * sizeof(float));

  k_detect<<<1, 64, 0, stream>>>((const unsigned short*)d_in[2], flag);

  run_pipeline<bf16_t, bf16_t, false>(d_in, N, E, d_out, Wpack, s0, s1, s2, s3, h2, Rn2, flag, 0,
                                      stream);
  run_pipeline<float, float, true>(d_in, N, E, d_out, Wpack, s0, s1, s2, s3, h2, Rn2, flag, 1,
                                   stream);
}

// Round 2
// 956.193 us; speedup vs baseline: 5.0229x; 2.1888x over previous
//
#include <hip/hip_runtime.h>

#define INV_SQRT_2 0.70710678118654752440f
#define INV_SQRT_3 0.57735026918962576451f

typedef __bf16 bf16_t;
typedef __bf16 bf16x8 __attribute__((ext_vector_type(8)));
typedef __bf16 bf16x4 __attribute__((ext_vector_type(4)));
typedef float f32x4 __attribute__((ext_vector_type(4)));

__device__ __forceinline__ float toF(float x) { return x; }
__device__ __forceinline__ float toF(bf16_t x) { return (float)x; }
__device__ __forceinline__ float siluf(float x) { return x / (1.f + __expf(-x)); }

template <typename T> __device__ __forceinline__ T fromF(float x);
template <> __device__ __forceinline__ float fromF<float>(float x) { return x; }
template <> __device__ __forceinline__ bf16_t fromF<bf16_t>(float x) { return (bf16_t)x; }

__device__ __forceinline__ bf16x8 ld8(const bf16_t* p) { return *(const bf16x8*)p; }
__device__ __forceinline__ bf16x8 ld8(const float* p) {
  bf16x8 r;
#pragma unroll
  for (int j = 0; j < 8; ++j) r[j] = (bf16_t)p[j];
  return r;
}

__device__ __forceinline__ f32x4 MFMA(bf16x8 a, bf16x8 b, f32x4 c) {
  return __builtin_amdgcn_mfma_f32_16x16x32_bf16(a, b, c, 0, 0, 0);
}

// Packed-B fragment: element j of lane l = B[ks*32 + (l>>4)*8 + j][nt*16 + (l&15)]
__device__ __forceinline__ bf16x8 ldB(const bf16_t* Bp, int ks, int nt, int NT, int lane) {
  return *(const bf16x8*)(Bp + ((((size_t)ks * NT + nt) * 64 + lane) << 3));
}

// hi/lo split accumulate: each matrix packed as [hi(SZ) | lo(SZ)].
// WS=true (f32 input path): W = hi + lo keeps near-f32 weight precision.
template <bool WS, int SZ>
__device__ __forceinline__ f32x4 mfma2(bf16x8 a, const bf16_t* Bp, int ks, int nt, int NT,
                                       int lane, f32x4 c) {
  c = MFMA(a, ldB(Bp, ks, nt, NT, lane), c);
  if (WS) c = MFMA(a, ldB(Bp + SZ, ks, nt, NT, lane), c);
  return c;
}

// ---- dtype detector: probe rbf_h (uniform [0,1]) interpreted as bf16 words.
__global__ void k_detect(const unsigned short* __restrict__ probe, int* __restrict__ flag) {
  __shared__ int cnt;
  if (threadIdx.x == 0) cnt = 0;
  __syncthreads();
  int bad = 0;
  for (int i = threadIdx.x; i < 256; i += 64) {
    unsigned int u = (unsigned int)probe[i] << 16;
    float v = __uint_as_float(u);
    if (!(v == v) || fabsf(v) > 4.f || v < -0.25f) bad++;
  }
  atomicAdd(&cnt, bad);
  __syncthreads();
  if (threadIdx.x == 0) *flag = (cnt > 16) ? 1 : 0;
}

__global__ void k_zero(float* __restrict__ p, int n) {
  int i = blockIdx.x * blockDim.x + threadIdx.x;
  if (i < n) p[i] = 0.f;
}

#define GUARD if (*flag != want) return;

// ---------------- weight repack: W(KxN) -> fragment-linear [hi|lo] ----------------
// mode 0: plain KxN row-major source.
// mode 1: bilinear (I=64,B=16,O=64) source, flattened K index kk = b*64 + i.
struct RDesc { const void* src; int K, N, Kpad, dstoff, mode; };
struct RTable { RDesc d[25]; };

template <typename TIN>
__global__ void k_repack(const int* __restrict__ flag, int want, RTable tab,
                         bf16_t* __restrict__ out) {
  GUARD
  RDesc d = tab.d[blockIdx.y];
  int p = blockIdx.x * 256 + threadIdx.x;
  int sz = d.Kpad * d.N;
  if (p >= sz) return;
  int NT = d.N >> 4;
  int j = p & 7;
  int lane = (p >> 3) & 63;
  int q = p >> 9;
  int nt = q % NT, ks = q / NT;
  int k = ks * 32 + ((lane >> 4) << 3) + j;
  int col = nt * 16 + (lane & 15);
  size_t si = d.mode ? ((size_t)(k & 63) * 16 + (k >> 6)) * 64 + col
                     : (size_t)k * d.N + col;
  float v = (k < d.K) ? toF(((const TIN*)d.src)[si]) : 0.f;
  bf16_t hi = (bf16_t)v;
  out[d.dstoff + p] = hi;
  out[d.dstoff + sz + p] = (bf16_t)(v - (float)hi);
}

// ---------------- plain GEMM + silu: out(bf16, M x NT*16) = silu(A @ W) ----------------
template <typename TA, int NT, int KSTEPS, bool WS>
__global__ __launch_bounds__(256) void k_gemm_mf(const int* __restrict__ flag, int want,
    const TA* __restrict__ A, const bf16_t* __restrict__ Bp, bf16_t* __restrict__ out, int M) {
  GUARD
  const int lane = threadIdx.x & 63, wid = threadIdx.x >> 6;
  const int row0 = (blockIdx.x * 4 + wid) << 4;
  if (row0 >= M) return;
  const int rc = lane & 15, g = lane >> 4;
  const int K = KSTEPS * 32;
  const TA* ap = A + (size_t)(row0 + rc) * K;
  f32x4 acc[NT] = {};
#pragma unroll
  for (int ks = 0; ks < KSTEPS; ++ks) {
    bf16x8 a = ld8(ap + ks * 32 + g * 8);
#pragma unroll
    for (int nt = 0; nt < NT; ++nt)
      acc[nt] = mfma2<WS, KSTEPS * 32 * NT * 16>(a, Bp, ks, nt, NT, lane, acc[nt]);
  }
  const int Nc = NT * 16;
  bf16_t* op = out + (size_t)(row0 + g * 4) * Nc + rc;
#pragma unroll
  for (int nt = 0; nt < NT; ++nt)
#pragma unroll
    for (int r = 0; r < 4; ++r) op[(size_t)r * Nc + nt * 16] = (bf16_t)siluf(acc[nt][r]);
}

// ---- m_kt pre: out = silu(m_st @ Wt_mkt) * (rbf3 @ Wt_rbf), K_gate=16 zero-padded to 32 ----
template <typename TIN, bool WS>
__global__ __launch_bounds__(256) void k_mkt_mf(const int* __restrict__ flag, int want,
    const TIN* __restrict__ mst, const TIN* __restrict__ rbf3,
    const bf16_t* __restrict__ Wm, const bf16_t* __restrict__ Wr,
    bf16_t* __restrict__ out, int M) {
  GUARD
  const int lane = threadIdx.x & 63, wid = threadIdx.x >> 6;
  const int row0 = (blockIdx.x * 4 + wid) << 4;
  if (row0 >= M) return;
  const int rc = lane & 15, g = lane >> 4;
  const TIN* ap = mst + (size_t)(row0 + rc) * 128;
  f32x4 am[8] = {}, ag[8] = {};
#pragma unroll
  for (int ks = 0; ks < 4; ++ks) {
    bf16x8 a = ld8(ap + ks * 32 + g * 8);
#pragma unroll
    for (int nt = 0; nt < 8; ++nt) am[nt] = mfma2<WS, 16384>(a, Wm, ks, nt, 8, lane, am[nt]);
  }
  bf16x8 az = {};
  if (g < 2) az = ld8(rbf3 + (size_t)(row0 + rc) * 16 + g * 8);
#pragma unroll
  for (int nt = 0; nt < 8; ++nt) ag[nt] = mfma2<WS, 4096>(az, Wr, 0, nt, 8, lane, ag[nt]);
  bf16_t* op = out + (size_t)(row0 + g * 4) * 128 + rc;
#pragma unroll
  for (int nt = 0; nt < 8; ++nt)
#pragma unroll
    for (int r = 0; r < 4; ++r)
      op[(size_t)r * 128 + nt * 16] = (bf16_t)(siluf(am[nt][r]) * ag[nt][r]);
}

// ---- MFMA bilinear: 16 edges/block, 256 threads ----
// Stage 1 (VALU): P[e][b*64+i] = sum_k basis[t,b]*m[gidx[t],i], written fragment-linear bf16.
// Stage 2 (MFMA): out[16 x 64] = P(16x1024) @ Wflat(1024x64), W fragment-packed [hi|lo].
template <typename TIN, bool WS>
__global__ __launch_bounds__(256) void k_bil_mf(const int* __restrict__ flag, int want,
    const TIN* __restrict__ basis, const bf16_t* __restrict__ msrc,
    const int* __restrict__ gidx, const bf16_t* __restrict__ Wc,
    bf16_t* __restrict__ out) {
  GUARD
  __shared__ __align__(16) bf16_t Ms[96 * 72];   // gathered m rows, stride 72 (pad)
  __shared__ __align__(16) float Bas[16 * 100];  // basis f32, per-edge stride 100 (pad)
  __shared__ __align__(16) bf16_t P[16384];      // A-fragment-linear sum_k (32 ks x 64 lane x 8)
  const int tid = threadIdx.x;
  const int e0 = blockIdx.x * 16;
  // stage gathered m rows (96 rows x 64 bf16)
#pragma unroll
  for (int it = 0; it < 3; ++it) {
    int c = tid + it * 256;  // 0..767 : 16B chunks
    int j = c >> 3, part = c & 7;
    int row = gidx[e0 * 6 + j];
    *(bf16x8*)&Ms[j * 72 + part * 8] = ld8(msrc + (size_t)row * 64 + part * 8);
  }
  // stage basis as f32 (exact), 16 edges x 96 contiguous elems
#pragma unroll
  for (int it = 0; it < 6; ++it) {
    int c = tid + it * 256;  // 0..1535
    Bas[(c / 96) * 100 + (c % 96)] = toF(basis[(size_t)e0 * 96 + c]);
  }
  __syncthreads();
  // stage 1: thread owns edge e = tid>>4, i-range i0..i0+3, all 16 b
  {
    const int e = tid >> 4, sub = tid & 15, i0 = sub * 4;
    float acc[16][4];
#pragma unroll
    for (int b = 0; b < 16; ++b)
#pragma unroll
      for (int j = 0; j < 4; ++j) acc[b][j] = 0.f;
#pragma unroll
    for (int k = 0; k < 6; ++k) {
      bf16x4 mv = *(const bf16x4*)&Ms[(e * 6 + k) * 72 + i0];
      float mf[4];
#pragma unroll
      for (int j = 0; j < 4; ++j) mf[j] = (float)mv[j];
      const float* bp = &Bas[e * 100 + k * 16];
#pragma unroll
      for (int b4 = 0; b4 < 4; ++b4) {
        f32x4 bv = *(const f32x4*)&bp[b4 * 4];
#pragma unroll
        for (int bb = 0; bb < 4; ++bb)
#pragma unroll
          for (int j = 0; j < 4; ++j) acc[b4 * 4 + bb][j] += bv[bb] * mf[j];
      }
    }
    // write P fragment-linear: elem (ks*64 + lane)*8 + jj ; lane = lane_hi*16 + e
#pragma unroll
    for (int b = 0; b < 16; ++b) {
      int kk = b * 64 + i0;
      int ks = kk >> 5, r5 = kk & 31;
      int lane_hi = r5 >> 3, jj = r5 & 7;
      bf16x4 w;
#pragma unroll
      for (int j = 0; j < 4; ++j) w[j] = (bf16_t)acc[b][j];
      *(bf16x4*)&P[ks * 512 + lane_hi * 128 + e * 8 + jj] = w;
    }
  }
  __syncthreads();
  // stage 2: (16 x 1024) @ (1024 x 64); wave w handles output cols w*16..w*16+15
  const int lane = tid & 63, wid = tid >> 6;
  const int rc = lane & 15, g = lane >> 4;
  f32x4 oacc = {};
#pragma unroll
  for (int ks = 0; ks < 32; ++ks) {
    bf16x8 a = *(const bf16x8*)&P[ks * 512 + lane * 8];
    oacc = mfma2<WS, 65536>(a, Wc, ks, wid, 4, lane, oacc);
  }
  bf16_t* op = out + ((size_t)e0 + g * 4) * 64 + wid * 16 + rc;
#pragma unroll
  for (int r = 0; r < 4; ++r) op[(size_t)r * 64] = (bf16_t)oacc[r];
}

// ---- fused combine (5 GEMM groups, swap-gather on A-fragment rows) -> X ----
template <typename TIN, bool WS>
__global__ __launch_bounds__(256) void k_comb_mf(const int* __restrict__ flag, int want,
    const TIN* __restrict__ mst, const bf16_t* __restrict__ xt, const bf16_t* __restrict__ xq,
    const int* __restrict__ idx_swap,
    const bf16_t* Wsk, const bf16_t* Wtst, const bf16_t* Wtts,
    const bf16_t* Wqst, const bf16_t* Wqts,
    bf16_t* __restrict__ X, int M) {
  GUARD
  const int lane = threadIdx.x & 63, wid = threadIdx.x >> 6;
  const int row0 = (blockIdx.x * 4 + wid) << 4;
  if (row0 >= M) return;
  const int rc = lane & 15, g = lane >> 4;
  const int arow = row0 + rc;
  const int srow = idx_swap[arow];
  const int nb = blockIdx.y * 4;  // column-half: nt in [nb, nb+4)
  f32x4 aV[4] = {}, a3[4] = {}, b3[4] = {}, a4[4] = {}, b4[4] = {};
#pragma unroll
  for (int ks = 0; ks < 4; ++ks) {
    bf16x8 a = ld8(mst + (size_t)arow * 128 + ks * 32 + g * 8);
#pragma unroll
    for (int t = 0; t < 4; ++t) aV[t] = mfma2<WS, 16384>(a, Wsk, ks, nb + t, 8, lane, aV[t]);
  }
#pragma unroll
  for (int ks = 0; ks < 2; ++ks) {
    bf16x8 a = ld8(xt + (size_t)arow * 64 + ks * 32 + g * 8);
#pragma unroll
    for (int t = 0; t < 4; ++t) a3[t] = mfma2<WS, 8192>(a, Wtst, ks, nb + t, 8, lane, a3[t]);
  }
#pragma unroll
  for (int ks = 0; ks < 2; ++ks) {
    bf16x8 a = ld8(xt + (size_t)srow * 64 + ks * 32 + g * 8);
#pragma unroll
    for (int t = 0; t < 4; ++t) b3[t] = mfma2<WS, 8192>(a, Wtts, ks, nb + t, 8, lane, b3[t]);
  }
#pragma unroll
  for (int ks = 0; ks < 2; ++ks) {
    bf16x8 a = ld8(xq + (size_t)arow * 64 + ks * 32 + g * 8);
#pragma unroll
    for (int t = 0; t < 4; ++t) a4[t] = mfma2<WS, 8192>(a, Wqst, ks, nb + t, 8, lane, a4[t]);
  }
#pragma unroll
  for (int ks = 0; ks < 2; ++ks) {
    bf16x8 a = ld8(xq + (size_t)srow * 64 + ks * 32 + g * 8);
#pragma unroll
    for (int t = 0; t < 4; ++t) b4[t] = mfma2<WS, 8192>(a, Wqts, ks, nb + t, 8, lane, b4[t]);
  }
  bf16_t* op = X + (size_t)(row0 + g * 4) * 128 + rc;
#pragma unroll
  for (int t = 0; t < 4; ++t)
#pragma unroll
    for (int r = 0; r < 4; ++r) {
      float v = aV[t][r] * INV_SQRT_3 +
                (siluf(a3[t][r]) + siluf(b3[t][r])) * (INV_SQRT_2 * INV_SQRT_3) +
                (siluf(a4[t][r]) + siluf(b4[t][r])) * (INV_SQRT_2 * INV_SQRT_3);
      op[(size_t)r * 128 + (nb + t) * 16] = (bf16_t)v;
    }
}

// ---- one residual layer on a wave's 16-row LDS slab: x = (x + silu(silu(x@W0)@W1))*r2 ----
template <bool WS>
__device__ __forceinline__ void res_layer(bf16_t* Xs, bf16_t* Ys, const bf16_t* W0,
                                          const bf16_t* W1, int wrow0, int lane) {
  const int rc = lane & 15, g = lane >> 4;
  f32x4 acc[8] = {};
#pragma unroll
  for (int ks = 0; ks < 4; ++ks) {
    bf16x8 a = *(const bf16x8*)&Xs[(wrow0 + rc) * 136 + ks * 32 + g * 8];
#pragma unroll
    for (int nt = 0; nt < 8; ++nt) acc[nt] = mfma2<WS, 16384>(a, W0, ks, nt, 8, lane, acc[nt]);
  }
#pragma unroll
  for (int nt = 0; nt < 8; ++nt)
#pragma unroll
    for (int r = 0; r < 4; ++r)
      Ys[(wrow0 + g * 4 + r) * 136 + nt * 16 + rc] = (bf16_t)siluf(acc[nt][r]);
  f32x4 a2[8] = {};
#pragma unroll
  for (int ks = 0; ks < 4; ++ks) {
    bf16x8 a = *(const bf16x8*)&Ys[(wrow0 + rc) * 136 + ks * 32 + g * 8];
#pragma unroll
    for (int nt = 0; nt < 8; ++nt) a2[nt] = mfma2<WS, 16384>(a, W1, ks, nt, 8, lane, a2[nt]);
  }
#pragma unroll
  for (int nt = 0; nt < 8; ++nt)
#pragma unroll
    for (int r = 0; r < 4; ++r) {
      int ix = (wrow0 + g * 4 + r) * 136 + nt * 16 + rc;
      Xs[ix] = (bf16_t)(((float)Xs[ix] + siluf(a2[nt][r])) * INV_SQRT_2);
    }
}

// ---- fused: x=res_before(X); m=(m_st+x)*r2; m=res_after(m) -> out ----
template <typename TIN, bool WS>
__global__ __launch_bounds__(256) void k_resE(const int* __restrict__ flag, int want,
    const bf16_t* __restrict__ Xg, const TIN* __restrict__ mst,
    const bf16_t* W0b, const bf16_t* W1b,
    const bf16_t* W0a, const bf16_t* W1a, const bf16_t* W2a, const bf16_t* W3a,
    bf16_t* __restrict__ outg, int M) {
  GUARD
  __shared__ __align__(16) bf16_t Xs[64 * 136];
  __shared__ __align__(16) bf16_t Ys[64 * 136];
  const int lane = threadIdx.x & 63, wid = threadIdx.x >> 6;
  const int grow0 = blockIdx.x * 64 + wid * 16;
  if (grow0 >= M) return;
  const int wrow0 = wid * 16;
#pragma unroll
  for (int i = 0; i < 4; ++i) {
    int o = i * 512 + lane * 8, r = o >> 7, c = o & 127;
    *(bf16x8*)&Xs[(wrow0 + r) * 136 + c] = *(const bf16x8*)&Xg[(size_t)(grow0 + r) * 128 + c];
  }
  res_layer<WS>(Xs, Ys, W0b, W1b, wrow0, lane);
#pragma unroll
  for (int i = 0; i < 4; ++i) {
    int o = i * 512 + lane * 8, r = o >> 7, c = o & 127;
    const TIN* mp = mst + (size_t)(grow0 + r) * 128 + c;
    bf16_t* xp = &Xs[(wrow0 + r) * 136 + c];
#pragma unroll
    for (int j = 0; j < 8; ++j) xp[j] = (bf16_t)((toF(mp[j]) + (float)xp[j]) * INV_SQRT_2);
  }
  res_layer<WS>(Xs, Ys, W0a, W1a, wrow0, lane);
  res_layer<WS>(Xs, Ys, W2a, W3a, wrow0, lane);
#pragma unroll
  for (int i = 0; i < 4; ++i) {
    int o = i * 512 + lane * 8, r = o >> 7, c = o & 127;
    *(bf16x8*)&outg[(size_t)(grow0 + r) * 128 + c] = *(const bf16x8*)&Xs[(wrow0 + r) * 136 + c];
  }
}

// ---- 2-layer residual stack, in place ----
template <bool WS>
__global__ __launch_bounds__(256) void k_resN(const int* __restrict__ flag, int want,
    bf16_t* __restrict__ Xg, const bf16_t* W0, const bf16_t* W1, const bf16_t* W2,
    const bf16_t* W3, int M) {
  GUARD
  __shared__ __align__(16) bf16_t Xs[64 * 136];
  __shared__ __align__(16) bf16_t Ys[64 * 136];
  const int lane = threadIdx.x & 63, wid = threadIdx.x >> 6;
  const int grow0 = blockIdx.x * 64 + wid * 16;
  if (grow0 >= M) return;
  const int wrow0 = wid * 16;
#pragma unroll
  for (int i = 0; i < 4; ++i) {
    int o = i * 512 + lane * 8, r = o >> 7, c = o & 127;
    *(bf16x8*)&Xs[(wrow0 + r) * 136 + c] = *(const bf16x8*)&Xg[(size_t)(grow0 + r) * 128 + c];
  }
  res_layer<WS>(Xs, Ys, W0, W1, wrow0, lane);
  res_layer<WS>(Xs, Ys, W2, W3, wrow0, lane);
#pragma unroll
  for (int i = 0; i < 4; ++i) {
    int o = i * 512 + lane * 8, r = o >> 7, c = o & 127;
    *(bf16x8*)&Xg[(size_t)(grow0 + r) * 128 + c] = *(const bf16x8*)&Xs[(wrow0 + r) * 136 + c];
  }
}

// ---- atom embedding scatter ----
template <typename TIN>
__global__ void k_scatter(const int* __restrict__ flag, int want,
                          const bf16_t* __restrict__ m, const TIN* __restrict__ rbf_h,
                          const TIN* __restrict__ Wrbf, const int* __restrict__ idx_t,
                          float* __restrict__ h2) {
  GUARD
  int e = blockIdx.x;
  int c = threadIdx.x;
  float g = 0.f;
#pragma unroll
  for (int k = 0; k < 16; ++k) g += toF(rbf_h[(size_t)e * 16 + k]) * toF(Wrbf[k * 128 + c]);
  atomicAdd(&h2[(size_t)idx_t[e] * 128 + c], (float)m[(size_t)e * 128 + c] * g);
}

// ---- h_new = (h + X)*r2 -> out (TOUT) and X (bf16, for ASI) ----
template <typename TIN, typename TOUT>
__global__ void k_hnew_b(const int* __restrict__ flag, int want,
                         const TIN* __restrict__ h, bf16_t* __restrict__ X,
                         TOUT* __restrict__ out, int n) {
  GUARD
  int i = blockIdx.x * blockDim.x + threadIdx.x;
  if (i >= n) return;
  float v = (toF(h[i]) + (float)X[i]) * INV_SQRT_2;
  X[i] = (bf16_t)v;
  out[i] = fromF<TOUT>(v);
}

// ---- fused ASI + res_m + final combine ----
template <typename TIN, typename TOUT, bool WS>
__global__ __launch_bounds__(256) void k_asi_res(const int* __restrict__ flag, int want,
    const bf16_t* __restrict__ hnew, const bf16_t* __restrict__ m,
    const int* __restrict__ idx_s, const int* __restrict__ idx_t,
    const bf16_t* Wasi, const bf16_t* Wm0, const bf16_t* Wm1,
    TOUT* __restrict__ outm, int M) {
  GUARD
  __shared__ __align__(16) bf16_t Xs[64 * 136];
  __shared__ __align__(16) bf16_t Ys[64 * 136];
  const int lane = threadIdx.x & 63, wid = threadIdx.x >> 6;
  const int grow0 = blockIdx.x * 64 + wid * 16;
  if (grow0 >= M) return;
  const int wrow0 = wid * 16;
  const int rc = lane & 15, g = lane >> 4;
  const int e = grow0 + rc;
  const int rs = idx_s[e], rt = idx_t[e];
  f32x4 acc[8] = {};
#pragma unroll
  for (int ks = 0; ks < 12; ++ks) {
    const bf16_t* src = (ks < 4) ? hnew + (size_t)rs * 128
                       : (ks < 8) ? hnew + (size_t)rt * 128
                                  : m + (size_t)e * 128;
    bf16x8 a = ld8(src + (ks & 3) * 32 + g * 8);
#pragma unroll
    for (int nt = 0; nt < 8; ++nt) acc[nt] = mfma2<WS, 49152>(a, Wasi, ks, nt, 8, lane, acc[nt]);
  }
#pragma unroll
  for (int nt = 0; nt < 8; ++nt)
#pragma unroll
    for (int r = 0; r < 4; ++r)
      Xs[(wrow0 + g * 4 + r) * 136 + nt * 16 + rc] = (bf16_t)siluf(acc[nt][r]);
  f32x4 a1[8] = {};
#pragma unroll
  for (int ks = 0; ks < 4; ++ks) {
    bf16x8 a = *(const bf16x8*)&Xs[(wrow0 + rc) * 136 + ks * 32 + g * 8];
#pragma unroll
    for (int nt = 0; nt < 8; ++nt) a1[nt] = mfma2<WS, 16384>(a, Wm0, ks, nt, 8, lane, a1[nt]);
  }
#pragma unroll
  for (int nt = 0; nt < 8; ++nt)
#pragma unroll
    for (int r = 0; r < 4; ++r)
      Ys[(wrow0 + g * 4 + r) * 136 + nt * 16 + rc] = (bf16_t)siluf(a1[nt][r]);
  f32x4 a2[8] = {};
#pragma unroll
  for (int ks = 0; ks < 4; ++ks) {
    bf16x8 a = *(const bf16x8*)&Ys[(wrow0 + rc) * 136 + ks * 32 + g * 8];
#pragma unroll
    for (int nt = 0; nt < 8; ++nt) a2[nt] = mfma2<WS, 16384>(a, Wm1, ks, nt, 8, lane, a2[nt]);
  }
#pragma unroll
  for (int nt = 0; nt < 8; ++nt)
#pragma unroll
    for (int r = 0; r < 4; ++r) {
      int row = grow0 + g * 4 + r, col = nt * 16 + rc;
      float x = (float)Xs[(wrow0 + g * 4 + r) * 136 + col];
      float v = (x + siluf(a2[nt][r])) * INV_SQRT_2;
      outm[(size_t)row * 128 + col] = fromF<TOUT>(((float)m[(size_t)row * 128 + col] + v) * INV_SQRT_2);
    }
}

// ================================================================================
template <typename TIN, typename TOUT, bool WS>
static void run_pipeline(void* const* d_in, int N, int E, void* d_out,
                         bf16_t* Wpack, bf16_t* s0, bf16_t* s1, bf16_t* s2, bf16_t* s3,
                         float* h2, bf16_t* Rn2, const int* flag, int want, hipStream_t stream) {
  const TIN* h      = (const TIN*)d_in[0];
  const TIN* m_st   = (const TIN*)d_in[1];
  const TIN* rbf_h  = (const TIN*)d_in[2];
  const TIN* rbf3   = (const TIN*)d_in[3];
  const TIN* cbf3   = (const TIN*)d_in[4];
  const TIN* sbf4   = (const TIN*)d_in[5];
  const int* idx_s   = (const int*)d_in[6];
  const int* idx_t   = (const int*)d_in[7];
  const int* idx_sw  = (const int*)d_in[8];
  const int* id3_kt  = (const int*)d_in[9];
  const int* enb_idx = (const int*)d_in[12];
  const TIN* Wt_mkt   = (const TIN*)d_in[17];
  const TIN* Wt_rbf   = (const TIN*)d_in[18];
  const TIN* Wt_down  = (const TIN*)d_in[19];
  const TIN* Wt_cbf   = (const TIN*)d_in[20];
  const TIN* Wt_up_st = (const TIN*)d_in[21];
  const TIN* Wt_up_ts = (const TIN*)d_in[22];
  const TIN* Wq_down  = (const TIN*)d_in[23];
  const TIN* Wq_sbf   = (const TIN*)d_in[24];
  const TIN* Wq_up_st = (const TIN*)d_in[25];
  const TIN* Wq_up_ts = (const TIN*)d_in[26];
  const TIN* Wres_before = (const TIN*)d_in[27];
  const TIN* Wres_after  = (const TIN*)d_in[28];
  const TIN* Wres_m      = (const TIN*)d_in[29];
  const TIN* W_ae_rbf    = (const TIN*)d_in[30];
  const TIN* W_ae_dense  = (const TIN*)d_in[31];
  const TIN* W_ae_res    = (const TIN*)d_in[32];
  const TIN* W_asi       = (const TIN*)d_in[33];
  const TIN* W_skip      = (const TIN*)d_in[16];

  RTable tab;
  int cur = 0, nd = 0;
  auto add = [&](const void* src, int K, int Np, int Kpad, int mode = 0) {
    tab.d[nd].src = src; tab.d[nd].K = K; tab.d[nd].N = Np; tab.d[nd].Kpad = Kpad;
    tab.d[nd].dstoff = cur; tab.d[nd].mode = mode;
    int o = cur;
    cur += 2 * Kpad * Np;  // hi + lo
    ++nd;
    return o;
  };
  const int M128 = 128 * 128;
  int oQd  = add(Wq_down, 128, 64, 128);
  int oMkt = add(Wt_mkt, 128, 128, 128);
  int oRbf = add(Wt_rbf, 16, 128, 32);
  int oTd  = add(Wt_down, 128, 64, 128);
  int oTst = add(Wt_up_st, 64, 128, 64);
  int oTts = add(Wt_up_ts, 64, 128, 64);
  int oQst = add(Wq_up_st, 64, 128, 64);
  int oQts = add(Wq_up_ts, 64, 128, 64);
  int oSk  = add(W_skip, 128, 128, 128);
  int oB0  = add(Wres_before, 128, 128, 128);
  int oB1  = add(Wres_before + M128, 128, 128, 128);
  int oA0  = add(Wres_after, 128, 128, 128);
  int oA1  = add(Wres_after + M128, 128, 128, 128);
  int oA2  = add(Wres_after + 2 * M128, 128, 128, 128);
  int oA3  = add(Wres_after + 3 * M128, 128, 128, 128);
  int oM0  = add(Wres_m, 128, 128, 128);
  int oM1  = add(Wres_m + M128, 128, 128, 128);
  int oAed = add(W_ae_dense, 128, 128, 128);
  int oAe0 = add(W_ae_res, 128, 128, 128);
  int oAe1 = add(W_ae_res + M128, 128, 128, 128);
  int oAe2 = add(W_ae_res + 2 * M128, 128, 128, 128);
  int oAe3 = add(W_ae_res + 3 * M128, 128, 128, 128);
  int oAsi = add(W_asi, 384, 128, 384);
  int oTc  = add(Wt_cbf, 1024, 64, 1024, 1);   // bilinear W, (i,b,o)->(b*64+i, o)
  int oQc  = add(Wq_sbf, 1024, 64, 1024, 1);
  (void)cur;

  const int gE = E / 64;   // 1250
  const int gN = N / 64;   // 125
  const int BS = 256;

  // workspace overlays (U = E*64 bf16):
  bf16_t* mkt_tmp = s0;  // spans s0+s1 (E x 128)
  bf16_t* m_kt = s2;
  bf16_t* m_d  = s3;
  bf16_t* xt = s0;
  bf16_t* xq = s1;
  bf16_t* X  = s2;       // spans s2+s3 (E x 128)
  bf16_t* R2 = s0;       // spans s0+s1 (E x 128) -- "m" after res stack

  k_repack<TIN><<<dim3(256, 25), BS, 0, stream>>>(flag, want, tab, Wpack);

  k_mkt_mf<TIN, WS><<<gE, BS, 0, stream>>>(flag, want, m_st, rbf3, Wpack + oMkt, Wpack + oRbf,
                                           mkt_tmp, E);
  k_gemm_mf<bf16_t, 4, 4, WS><<<gE, BS, 0, stream>>>(flag, want, mkt_tmp, Wpack + oTd, m_kt, E);
  k_gemm_mf<TIN, 4, 4, WS><<<gE, BS, 0, stream>>>(flag, want, m_st, Wpack + oQd, m_d, E);
  k_bil_mf<TIN, WS><<<E / 16, BS, 0, stream>>>(flag, want, cbf3, m_kt, id3_kt, Wpack + oTc, xt);
  k_bil_mf<TIN, WS><<<E / 16, BS, 0, stream>>>(flag, want, sbf4, m_d, enb_idx, Wpack + oQc, xq);
  k_comb_mf<TIN, WS><<<dim3(gE, 2), BS, 0, stream>>>(flag, want, m_st, xt, xq, idx_sw,
      Wpack + oSk, Wpack + oTst, Wpack + oTts, Wpack + oQst, Wpack + oQts, X, E);
  k_resE<TIN, WS><<<gE, BS, 0, stream>>>(flag, want, X, m_st,
      Wpack + oB0, Wpack + oB1, Wpack + oA0, Wpack + oA1, Wpack + oA2, Wpack + oA3, R2, E);
  // h2 overlays the (now dead) X region; zero then scatter
  k_zero<<<(N * 128 + BS - 1) / BS, BS, 0, stream>>>(h2, N * 128);
  k_scatter<TIN><<<E, 128, 0, stream>>>(flag, want, R2, rbf_h, W_ae_rbf, idx_t, h2);
  k_gemm_mf<float, 8, 4, WS><<<gN, BS, 0, stream>>>(flag, want, h2, Wpack + oAed, Rn2, N);
  k_resN<WS><<<gN, BS, 0, stream>>>(flag, want, Rn2, Wpack + oAe0, Wpack + oAe1,
                                    Wpack + oAe2, Wpack + oAe3, N);
  TOUT* out_h = (TOUT*)d_out;
  TOUT* out_m = out_h + (size_t)N * 128;
  k_hnew_b<TIN, TOUT><<<(N * 128 + BS - 1) / BS, BS, 0, stream>>>(flag, want, h, Rn2, out_h,
                                                                  N * 128);
  k_asi_res<TIN, TOUT, WS><<<gE, BS, 0, stream>>>(flag, want, Rn2, R2, idx_s, idx_t,
      Wpack + oAsi, Wpack + oM0, Wpack + oM1, out_m, E);
}

extern "C" void kernel_launch(void* const* d_in, const int* in_sizes, int n_in,
                              void* d_out, int out_size, void* d_ws, size_t ws_size,
                              hipStream_t stream) {
  const int D = 128;
  const int N = in_sizes[0] / D;   // 8000
  const int E = in_sizes[1] / D;   // 80000

  // workspace: Wpack (958464 bf16 = 1,916,928 B) | flag | 4 slots of E*64 bf16 (~41 MB)
  char* base = (char*)d_ws;
  bf16_t* Wpack = (bf16_t*)base;
  int* flag = (int*)(base + 1916928);
  char* dyn = base + 1917184;
  size_t U = (size_t)E * 64 * sizeof(bf16_t);
  bf16_t* s0 = (bf16_t*)dyn;
  bf16_t* s1 = (bf16_t*)(dyn + U);
  bf16_t* s2 = (bf16_t*)(dyn + 2 * U);
  bf16_t* s3 = (bf16_t*)(dyn + 3 * U);
  float* h2 = (float*)(dyn + 2 * U);                              // reuses X region (dead by then)
  bf16_t* Rn2 = (bf16_t*)((char*)h2 + (size_t)N * 128 * sizeof(float));

  k_detect<<<1, 64, 0, stream>>>((const unsigned short*)d_in[2], flag);

  run_pipeline<bf16_t, bf16_t, false>(d_in, N, E, d_out, Wpack, s0, s1, s2, s3, h2, Rn2, flag, 0,
                                      stream);
  run_pipeline<float, float, true>(d_in, N, E, d_out, Wpack, s0, s1, s2, s3, h2, Rn2, flag, 1,
                                   stream);
}

// Round 3
// 669.348 us; speedup vs baseline: 7.1754x; 1.4285x over previous
//
#include <hip/hip_runtime.h>

#define INV_SQRT_2 0.70710678118654752440f
#define INV_SQRT_3 0.57735026918962576451f

typedef __bf16 bf16_t;
typedef __bf16 bf16x8 __attribute__((ext_vector_type(8)));
typedef __bf16 bf16x4 __attribute__((ext_vector_type(4)));
typedef float f32x4 __attribute__((ext_vector_type(4)));

__device__ __forceinline__ float toF(float x) { return x; }
__device__ __forceinline__ float toF(bf16_t x) { return (float)x; }
__device__ __forceinline__ float siluf(float x) { return x / (1.f + __expf(-x)); }

template <typename T> __device__ __forceinline__ T fromF(float x);
template <> __device__ __forceinline__ float fromF<float>(float x) { return x; }
template <> __device__ __forceinline__ bf16_t fromF<bf16_t>(float x) { return (bf16_t)x; }

__device__ __forceinline__ bf16x8 ld8(const bf16_t* p) { return *(const bf16x8*)p; }
__device__ __forceinline__ bf16x8 ld8(const float* p) {
  bf16x8 r;
#pragma unroll
  for (int j = 0; j < 8; ++j) r[j] = (bf16_t)p[j];
  return r;
}

__device__ __forceinline__ f32x4 MFMA(bf16x8 a, bf16x8 b, f32x4 c) {
  return __builtin_amdgcn_mfma_f32_16x16x32_bf16(a, b, c, 0, 0, 0);
}

__device__ __forceinline__ void zero8(f32x4 (&a)[8]) {
#pragma unroll
  for (int i = 0; i < 8; ++i)
#pragma unroll
    for (int q = 0; q < 4; ++q) a[i][q] = 0.f;
}
__device__ __forceinline__ void zero4(f32x4 (&a)[4]) {
#pragma unroll
  for (int i = 0; i < 4; ++i)
#pragma unroll
    for (int q = 0; q < 4; ++q) a[i][q] = 0.f;
}

// Packed-B fragment: element j of lane l = B[ks*32 + (l>>4)*8 + j][nt*16 + (l&15)]
__device__ __forceinline__ bf16x8 ldB(const bf16_t* Bp, int ks, int nt, int NT, int lane) {
  return *(const bf16x8*)(Bp + ((((size_t)ks * NT + nt) * 64 + lane) << 3));
}

// hi/lo split accumulate (global-B streaming form; used by k_bil_mf)
template <bool WS, int SZ>
__device__ __forceinline__ f32x4 mfma2(bf16x8 a, const bf16_t* Bp, int ks, int nt, int NT,
                                       int lane, f32x4 c) {
  c = MFMA(a, ldB(Bp, ks, nt, NT, lane), c);
  if (WS) c = MFMA(a, ldB(Bp + SZ, ks, nt, NT, lane), c);
  return c;
}

// ---- weight staging helpers: 512 threads move 16/32 KB global->regs->LDS ----
template <int NC>
struct StReg { bf16x8 v[NC]; };
template <int NC>
__device__ __forceinline__ void st_issue(StReg<NC>& r, const bf16_t* src, int tid) {
#pragma unroll
  for (int i = 0; i < NC; ++i) r.v[i] = *(const bf16x8*)(src + ((i * 512 + tid) << 3));
}
template <int NC>
__device__ __forceinline__ void st_commit(const StReg<NC>& r, bf16_t* dst, int tid) {
#pragma unroll
  for (int i = 0; i < NC; ++i) *(bf16x8*)&dst[(i * 512 + tid) << 3] = r.v[i];
}

// ---- MFMA pass over 16 rows from A-frag regs; B from LDS ----
template <int KS, int NT>
__device__ __forceinline__ void pass_glob(f32x4 (&acc)[NT], const bf16x8* af,
                                          const bf16_t* Wbuf, int lane) {
#pragma unroll
  for (int ks = 0; ks < KS; ++ks)
#pragma unroll
    for (int nt = 0; nt < NT; ++nt)
      acc[nt] = MFMA(af[ks], *(const bf16x8*)&Wbuf[((ks * NT + nt) * 64 + lane) << 3], acc[nt]);
}
// ---- MFMA pass; A from a 16-row LDS slab (stride 136), B from LDS ----
template <int KS>
__device__ __forceinline__ void pass_slab(f32x4 (&acc)[8], const bf16_t* slab,
                                          const bf16_t* Wbuf, int lane) {
  const int rc = lane & 15, g = lane >> 4;
#pragma unroll
  for (int ks = 0; ks < KS; ++ks) {
    bf16x8 a = *(const bf16x8*)&slab[rc * 136 + ks * 32 + (g << 3)];
#pragma unroll
    for (int nt = 0; nt < 8; ++nt)
      acc[nt] = MFMA(a, *(const bf16x8*)&Wbuf[((ks * 8 + nt) * 64 + lane) << 3], acc[nt]);
  }
}

// ---- dtype detector ----
__global__ void k_detect(const unsigned short* __restrict__ probe, int* __restrict__ flag) {
  __shared__ int cnt;
  if (threadIdx.x == 0) cnt = 0;
  __syncthreads();
  int bad = 0;
  for (int i = threadIdx.x; i < 256; i += 64) {
    unsigned int u = (unsigned int)probe[i] << 16;
    float v = __uint_as_float(u);
    if (!(v == v) || fabsf(v) > 4.f || v < -0.25f) bad++;
  }
  atomicAdd(&cnt, bad);
  __syncthreads();
  if (threadIdx.x == 0) *flag = (cnt > 16) ? 1 : 0;
}

__global__ void k_zero(float* __restrict__ p, int n) {
  int i = blockIdx.x * blockDim.x + threadIdx.x;
  if (i < n) p[i] = 0.f;
}

#define GUARD if (*flag != want) return;

// ---------------- weight repack: W(KxN) -> fragment-linear [hi|lo] ----------------
struct RDesc { const void* src; int K, N, Kpad, dstoff, mode; };
struct RTable { RDesc d[25]; };

template <typename TIN>
__global__ void k_repack(const int* __restrict__ flag, int want, RTable tab,
                         bf16_t* __restrict__ out) {
  GUARD
  RDesc d = tab.d[blockIdx.y];
  int p = blockIdx.x * 256 + threadIdx.x;
  int sz = d.Kpad * d.N;
  if (p >= sz) return;
  int NT = d.N >> 4;
  int j = p & 7;
  int lane = (p >> 3) & 63;
  int q = p >> 9;
  int nt = q % NT, ks = q / NT;
  int k = ks * 32 + ((lane >> 4) << 3) + j;
  int col = nt * 16 + (lane & 15);
  size_t si = d.mode ? ((size_t)(k & 63) * 16 + (k >> 6)) * 64 + col
                     : (size_t)k * d.N + col;
  float v = (k < d.K) ? toF(((const TIN*)d.src)[si]) : 0.f;
  bf16_t hi = (bf16_t)v;
  out[d.dstoff + p] = hi;
  out[d.dstoff + sz + p] = (bf16_t)(v - (float)hi);
}

// ---- MFMA bilinear: 16 edges/block, 256 threads ----
template <typename TIN, bool WS>
__global__ __launch_bounds__(256) void k_bil_mf(const int* __restrict__ flag, int want,
    const TIN* __restrict__ basis, const bf16_t* __restrict__ msrc,
    const int* __restrict__ gidx, const bf16_t* __restrict__ Wc,
    bf16_t* __restrict__ out) {
  GUARD
  __shared__ __align__(16) bf16_t Ms[96 * 72];
  __shared__ __align__(16) float Bas[16 * 100];
  __shared__ __align__(16) bf16_t P[16384];
  const int tid = threadIdx.x;
  const int e0 = blockIdx.x * 16;
#pragma unroll
  for (int it = 0; it < 3; ++it) {
    int c = tid + it * 256;
    int j = c >> 3, part = c & 7;
    int row = gidx[e0 * 6 + j];
    *(bf16x8*)&Ms[j * 72 + part * 8] = ld8(msrc + (size_t)row * 64 + part * 8);
  }
#pragma unroll
  for (int it = 0; it < 6; ++it) {
    int c = tid + it * 256;
    Bas[(c / 96) * 100 + (c % 96)] = toF(basis[(size_t)e0 * 96 + c]);
  }
  __syncthreads();
  {
    const int e = tid >> 4, sub = tid & 15, i0 = sub * 4;
    float acc[16][4];
#pragma unroll
    for (int b = 0; b < 16; ++b)
#pragma unroll
      for (int j = 0; j < 4; ++j) acc[b][j] = 0.f;
#pragma unroll
    for (int k = 0; k < 6; ++k) {
      bf16x4 mv = *(const bf16x4*)&Ms[(e * 6 + k) * 72 + i0];
      float mf[4];
#pragma unroll
      for (int j = 0; j < 4; ++j) mf[j] = (float)mv[j];
      const float* bp = &Bas[e * 100 + k * 16];
#pragma unroll
      for (int b4 = 0; b4 < 4; ++b4) {
        f32x4 bv = *(const f32x4*)&bp[b4 * 4];
#pragma unroll
        for (int bb = 0; bb < 4; ++bb)
#pragma unroll
          for (int j = 0; j < 4; ++j) acc[b4 * 4 + bb][j] += bv[bb] * mf[j];
      }
    }
#pragma unroll
    for (int b = 0; b < 16; ++b) {
      int kk = b * 64 + i0;
      int ks = kk >> 5, r5 = kk & 31;
      int lane_hi = r5 >> 3, jj = r5 & 7;
      bf16x4 w;
#pragma unroll
      for (int j = 0; j < 4; ++j) w[j] = (bf16_t)acc[b][j];
      *(bf16x4*)&P[ks * 512 + lane_hi * 128 + e * 8 + jj] = w;
    }
  }
  __syncthreads();
  const int lane = tid & 63, wid = tid >> 6;
  const int rc = lane & 15, g = lane >> 4;
  f32x4 oa[4];
  zero4(oa);
#pragma unroll
  for (int k4 = 0; k4 < 8; ++k4)
#pragma unroll
    for (int j = 0; j < 4; ++j) {
      int ks = k4 * 4 + j;
      oa[j] = mfma2<WS, 65536>(*(const bf16x8*)&P[ks * 512 + lane * 8], Wc, ks, wid, 4, lane,
                               oa[j]);
    }
  f32x4 oacc = (oa[0] + oa[1]) + (oa[2] + oa[3]);
  bf16_t* op = out + ((size_t)e0 + g * 4) * 64 + wid * 16 + rc;
#pragma unroll
  for (int r = 0; r < 4; ++r) op[(size_t)r * 64] = (bf16_t)oacc[r];
}

// ---- combine: 128 rows/block, 5 logical GEMMs, weights via LDS double buffer ----
template <typename TIN, bool WS>
__global__ __launch_bounds__(512, 2) void k_comb2(const int* __restrict__ flag, int want,
    const TIN* __restrict__ mst, const bf16_t* __restrict__ xt, const bf16_t* __restrict__ xq,
    const int* __restrict__ idx_swap,
    const bf16_t* Wsk, const bf16_t* Wtst, const bf16_t* Wtts,
    const bf16_t* Wqst, const bf16_t* Wqts,
    bf16_t* __restrict__ X, int M) {
  GUARD
  __shared__ __align__(16) bf16_t Wb[2][16384];
  const int tid = threadIdx.x;
  const int lane = tid & 63, wid = tid >> 6;
  const int grow0 = blockIdx.x * 128 + wid * 16;
  const int rc = lane & 15, g = lane >> 4;
  const int arow = grow0 + rc;
  const int srow = idx_swap[arow];

  const bf16_t* wseq[5] = {Wsk, Wtst, Wtts, Wqst, Wqts};
  const int SZs[5] = {16384, 8192, 8192, 8192, 8192};

  StReg<4> sreg;
  st_issue<4>(sreg, wseq[0], tid);
  st_commit<4>(sreg, Wb[0], tid);
  __syncthreads();
  int cur = 0;
  f32x4 total[8];
  f32x4 acc[8];
  zero8(acc);
  bf16x8 af[4];
#pragma unroll
  for (int l = 0; l < 5; ++l) {
    if (l == 0) {
#pragma unroll
      for (int ks = 0; ks < 4; ++ks)
        af[ks] = ld8(mst + (size_t)arow * 128 + ks * 32 + (g << 3));
    } else {
      const bf16_t* asrc = (l <= 2) ? xt : xq;
      int r = (l == 1 || l == 3) ? arow : srow;
#pragma unroll
      for (int ks = 0; ks < 2; ++ks) af[ks] = ld8(asrc + (size_t)r * 64 + ks * 32 + (g << 3));
    }
#pragma unroll
    for (int p = 0; p < (WS ? 2 : 1); ++p) {
      bool last_stage = (l == 4) && (p == (WS ? 1 : 0));
      if (!last_stage) {
        const bf16_t* nx = (WS && p == 0) ? wseq[l] + SZs[l] : wseq[l + 1];
        st_issue<4>(sreg, nx, tid);
      }
      if (l == 0) pass_glob<4, 8>(acc, af, Wb[cur], lane);
      else        pass_glob<2, 8>(acc, af, Wb[cur], lane);
      if (!last_stage) {
        st_commit<4>(sreg, Wb[cur ^ 1], tid);
        __syncthreads();
        cur ^= 1;
      }
    }
    if (l == 0) {
#pragma unroll
      for (int nt = 0; nt < 8; ++nt) total[nt] = acc[nt] * INV_SQRT_3;
    } else {
#pragma unroll
      for (int nt = 0; nt < 8; ++nt)
#pragma unroll
        for (int r = 0; r < 4; ++r)
          total[nt][r] += siluf(acc[nt][r]) * (INV_SQRT_2 * INV_SQRT_3);
    }
    zero8(acc);
  }
  bf16_t* op = X + (size_t)(grow0 + g * 4) * 128 + rc;
#pragma unroll
  for (int nt = 0; nt < 8; ++nt)
#pragma unroll
    for (int r = 0; r < 4; ++r) op[(size_t)r * 128 + nt * 16] = (bf16_t)total[nt][r];
}

// ---- resE: res_before + mst-mix + res_after(2 layers); 128 rows/block ----
template <typename TIN, bool WS>
__global__ __launch_bounds__(512, 1) void k_resE2(const int* __restrict__ flag, int want,
    const bf16_t* __restrict__ Xg, const TIN* __restrict__ mst,
    const bf16_t* W0, const bf16_t* W1, const bf16_t* W2,
    const bf16_t* W3, const bf16_t* W4, const bf16_t* W5,
    bf16_t* __restrict__ outg, int M) {
  GUARD
  __shared__ __align__(16) bf16_t Xs[128 * 136];
  __shared__ __align__(16) bf16_t Ys[128 * 136];
  __shared__ __align__(16) bf16_t Wb[2][16384];
  const int tid = threadIdx.x;
  const int lane = tid & 63, wid = tid >> 6;
  const int grow0 = blockIdx.x * 128 + wid * 16;
  const int rc = lane & 15, g = lane >> 4;
  bf16_t* slabX = Xs + wid * 16 * 136;
  bf16_t* slabY = Ys + wid * 16 * 136;

  const bf16_t* seq[12];
  if (WS) {
    seq[0] = W0; seq[1] = W0 + 16384; seq[2] = W1; seq[3] = W1 + 16384;
    seq[4] = W2; seq[5] = W2 + 16384; seq[6] = W3; seq[7] = W3 + 16384;
    seq[8] = W4; seq[9] = W4 + 16384; seq[10] = W5; seq[11] = W5 + 16384;
  } else {
    seq[0] = W0; seq[1] = W1; seq[2] = W2; seq[3] = W3; seq[4] = W4; seq[5] = W5;
  }
  const int NW = WS ? 12 : 6;

  StReg<4> sreg;
  st_issue<4>(sreg, seq[0], tid);
#pragma unroll
  for (int i = 0; i < 4; ++i) {
    int o = (i * 64 + lane) * 8;
    int r = o >> 7, c = o & 127;
    *(bf16x8*)&slabX[r * 136 + c] = ld8(Xg + (size_t)(grow0 + r) * 128 + c);
  }
  st_commit<4>(sreg, Wb[0], tid);
  __syncthreads();

  f32x4 acc[8];
  zero8(acc);
  int cur = 0;
#pragma unroll
  for (int s = 0; s < NW; ++s) {
    if (s + 1 < NW) st_issue<4>(sreg, seq[s + 1], tid);
    const int gg = WS ? (s >> 1) : s;
    const bool fin = WS ? ((s & 1) != 0) : true;
    pass_slab<4>(acc, (gg & 1) ? slabY : slabX, Wb[cur], lane);
    if (fin) {
      if ((gg & 1) == 0) {
#pragma unroll
        for (int nt = 0; nt < 8; ++nt)
#pragma unroll
          for (int r = 0; r < 4; ++r)
            slabY[(g * 4 + r) * 136 + nt * 16 + rc] = (bf16_t)siluf(acc[nt][r]);
      } else {
#pragma unroll
        for (int nt = 0; nt < 8; ++nt)
#pragma unroll
          for (int r = 0; r < 4; ++r) {
            int ix = (g * 4 + r) * 136 + nt * 16 + rc;
            float v = ((float)slabX[ix] + siluf(acc[nt][r])) * INV_SQRT_2;
            if (gg == 1) {
              float mv = toF(mst[(size_t)(grow0 + g * 4 + r) * 128 + nt * 16 + rc]);
              v = (mv + v) * INV_SQRT_2;
            }
            slabX[ix] = (bf16_t)v;
          }
      }
      zero8(acc);
    }
    if (s + 1 < NW) {
      st_commit<4>(sreg, Wb[cur ^ 1], tid);
      __syncthreads();
      cur ^= 1;
    }
  }
#pragma unroll
  for (int i = 0; i < 4; ++i) {
    int o = (i * 64 + lane) * 8;
    int r = o >> 7, c = o & 127;
    *(bf16x8*)&outg[(size_t)(grow0 + r) * 128 + c] = *(const bf16x8*)&slabX[r * 136 + c];
  }
}

// ---- resN: 2-layer residual stack, in place, partial-block safe ----
template <bool WS>
__global__ __launch_bounds__(512, 1) void k_resN2(const int* __restrict__ flag, int want,
    bf16_t* __restrict__ Xg, const bf16_t* W0, const bf16_t* W1, const bf16_t* W2,
    const bf16_t* W3, int M) {
  GUARD
  __shared__ __align__(16) bf16_t Xs[128 * 136];
  __shared__ __align__(16) bf16_t Ys[128 * 136];
  __shared__ __align__(16) bf16_t Wb[2][16384];
  const int tid = threadIdx.x;
  const int lane = tid & 63, wid = tid >> 6;
  const int grow0 = blockIdx.x * 128 + wid * 16;
  const bool act = grow0 < M;
  const int rc = lane & 15, g = lane >> 4;
  bf16_t* slabX = Xs + wid * 16 * 136;
  bf16_t* slabY = Ys + wid * 16 * 136;

  const bf16_t* seq[8];
  if (WS) {
    seq[0] = W0; seq[1] = W0 + 16384; seq[2] = W1; seq[3] = W1 + 16384;
    seq[4] = W2; seq[5] = W2 + 16384; seq[6] = W3; seq[7] = W3 + 16384;
  } else {
    seq[0] = W0; seq[1] = W1; seq[2] = W2; seq[3] = W3;
  }
  const int NW = WS ? 8 : 4;

  StReg<4> sreg;
  st_issue<4>(sreg, seq[0], tid);
  if (act) {
#pragma unroll
    for (int i = 0; i < 4; ++i) {
      int o = (i * 64 + lane) * 8;
      int r = o >> 7, c = o & 127;
      *(bf16x8*)&slabX[r * 136 + c] = ld8(Xg + (size_t)(grow0 + r) * 128 + c);
    }
  }
  st_commit<4>(sreg, Wb[0], tid);
  __syncthreads();

  f32x4 acc[8];
  zero8(acc);
  int cur = 0;
#pragma unroll
  for (int s = 0; s < NW; ++s) {
    if (s + 1 < NW) st_issue<4>(sreg, seq[s + 1], tid);
    const int gg = WS ? (s >> 1) : s;
    const bool fin = WS ? ((s & 1) != 0) : true;
    pass_slab<4>(acc, (gg & 1) ? slabY : slabX, Wb[cur], lane);
    if (fin) {
      if ((gg & 1) == 0) {
#pragma unroll
        for (int nt = 0; nt < 8; ++nt)
#pragma unroll
          for (int r = 0; r < 4; ++r)
            slabY[(g * 4 + r) * 136 + nt * 16 + rc] = (bf16_t)siluf(acc[nt][r]);
      } else {
#pragma unroll
        for (int nt = 0; nt < 8; ++nt)
#pragma unroll
          for (int r = 0; r < 4; ++r) {
            int ix = (g * 4 + r) * 136 + nt * 16 + rc;
            slabX[ix] = (bf16_t)(((float)slabX[ix] + siluf(acc[nt][r])) * INV_SQRT_2);
          }
      }
      zero8(acc);
    }
    if (s + 1 < NW) {
      st_commit<4>(sreg, Wb[cur ^ 1], tid);
      __syncthreads();
      cur ^= 1;
    }
  }
  if (act) {
#pragma unroll
    for (int i = 0; i < 4; ++i) {
      int o = (i * 64 + lane) * 8;
      int r = o >> 7, c = o & 127;
      *(bf16x8*)&Xg[(size_t)(grow0 + r) * 128 + c] = *(const bf16x8*)&slabX[r * 136 + c];
    }
  }
}

// ---- ASI(K=384, gathered A) + res_m + final combine; 128 rows/block ----
template <typename TIN, typename TOUT, bool WS>
__global__ __launch_bounds__(512, 1) void k_asi2(const int* __restrict__ flag, int want,
    const bf16_t* __restrict__ hnew, const bf16_t* __restrict__ m,
    const int* __restrict__ idx_s, const int* __restrict__ idx_t,
    const bf16_t* Wasi, const bf16_t* Wm0, const bf16_t* Wm1,
    TOUT* __restrict__ outm, int M) {
  GUARD
  __shared__ __align__(16) bf16_t Xs[128 * 136];
  __shared__ __align__(16) bf16_t Ys[128 * 136];
  __shared__ __align__(16) bf16_t Wb[2][16384];
  const int tid = threadIdx.x;
  const int lane = tid & 63, wid = tid >> 6;
  const int grow0 = blockIdx.x * 128 + wid * 16;
  const int rc = lane & 15, g = lane >> 4;
  bf16_t* slabX = Xs + wid * 16 * 136;
  bf16_t* slabY = Ys + wid * 16 * 136;
  const int e = grow0 + rc;
  const int rs = idx_s[e], rt = idx_t[e];

  const bf16_t* seq[10];
  if (WS) {
    seq[0] = Wasi;         seq[1] = Wasi + 49152;
    seq[2] = Wasi + 16384; seq[3] = Wasi + 65536;
    seq[4] = Wasi + 32768; seq[5] = Wasi + 81920;
    seq[6] = Wm0;          seq[7] = Wm0 + 16384;
    seq[8] = Wm1;          seq[9] = Wm1 + 16384;
  } else {
    seq[0] = Wasi; seq[1] = Wasi + 16384; seq[2] = Wasi + 32768;
    seq[3] = Wm0;  seq[4] = Wm1;
  }
  const int NW = WS ? 10 : 5;

  StReg<4> sreg;
  st_issue<4>(sreg, seq[0], tid);
  st_commit<4>(sreg, Wb[0], tid);
  __syncthreads();

  f32x4 acc[8];
  zero8(acc);
  bf16x8 af[4];
  int cur = 0;
#pragma unroll
  for (int s = 0; s < NW; ++s) {
    if (s + 1 < NW) st_issue<4>(sreg, seq[s + 1], tid);
    const int lg = WS ? (s >> 1) : s;
    const bool first = WS ? ((s & 1) == 0) : true;
    const bool fin = WS ? ((s & 1) != 0) : true;
    if (lg <= 2) {
      if (first) {
        const bf16_t* asrc = (lg == 0) ? hnew + (size_t)rs * 128
                           : (lg == 1) ? hnew + (size_t)rt * 128
                                       : m + (size_t)e * 128;
#pragma unroll
        for (int ks = 0; ks < 4; ++ks) af[ks] = ld8(asrc + ks * 32 + (g << 3));
      }
      pass_glob<4, 8>(acc, af, Wb[cur], lane);
    } else if (lg == 3) {
      pass_slab<4>(acc, slabX, Wb[cur], lane);
    } else {
      pass_slab<4>(acc, slabY, Wb[cur], lane);
    }
    if (fin) {
      if (lg == 2) {
#pragma unroll
        for (int nt = 0; nt < 8; ++nt)
#pragma unroll
          for (int r = 0; r < 4; ++r)
            slabX[(g * 4 + r) * 136 + nt * 16 + rc] = (bf16_t)siluf(acc[nt][r]);
        zero8(acc);
      } else if (lg == 3) {
#pragma unroll
        for (int nt = 0; nt < 8; ++nt)
#pragma unroll
          for (int r = 0; r < 4; ++r)
            slabY[(g * 4 + r) * 136 + nt * 16 + rc] = (bf16_t)siluf(acc[nt][r]);
        zero8(acc);
      } else if (lg == 4) {
#pragma unroll
        for (int nt = 0; nt < 8; ++nt)
#pragma unroll
          for (int r = 0; r < 4; ++r) {
            int row = grow0 + g * 4 + r, col = nt * 16 + rc;
            float x = (float)slabX[(g * 4 + r) * 136 + col];
            float v = (x + siluf(acc[nt][r])) * INV_SQRT_2;
            outm[(size_t)row * 128 + col] =
                fromF<TOUT>(((float)m[(size_t)row * 128 + col] + v) * INV_SQRT_2);
          }
      }
    }
    if (s + 1 < NW) {
      st_commit<4>(sreg, Wb[cur ^ 1], tid);
      __syncthreads();
      cur ^= 1;
    }
  }
}

// ---- m_kt pre: silu(m_st@Wm) * (rbf3@Wr); weights in LDS ----
template <typename TIN, bool WS>
__global__ __launch_bounds__(512, 2) void k_mkt2(const int* __restrict__ flag, int want,
    const TIN* __restrict__ mst, const TIN* __restrict__ rbf3,
    const bf16_t* __restrict__ Wm, const bf16_t* __restrict__ Wr,
    bf16_t* __restrict__ out, int M) {
  GUARD
  __shared__ __align__(16) bf16_t Wb[2][16384];
  __shared__ __align__(16) bf16_t Wrl[8192];
  const int tid = threadIdx.x;
  const int lane = tid & 63, wid = tid >> 6;
  const int grow0 = blockIdx.x * 128 + wid * 16;
  const int rc = lane & 15, g = lane >> 4;
  StReg<4> sreg;
  st_issue<4>(sreg, Wm, tid);
  bf16x8 wr0 = *(const bf16x8*)(Wr + (tid << 3));
  bf16x8 wr1 = *(const bf16x8*)(Wr + 4096 + (tid << 3));
  st_commit<4>(sreg, Wb[0], tid);
  *(bf16x8*)&Wrl[tid << 3] = wr0;
  *(bf16x8*)&Wrl[4096 + (tid << 3)] = wr1;
  __syncthreads();
  bf16x8 af[4];
#pragma unroll
  for (int ks = 0; ks < 4; ++ks)
    af[ks] = ld8(mst + (size_t)(grow0 + rc) * 128 + ks * 32 + (g << 3));
  bf16x8 az;
#pragma unroll
  for (int j = 0; j < 8; ++j) az[j] = (bf16_t)0.f;
  if (g < 2) az = ld8(rbf3 + (size_t)(grow0 + rc) * 16 + (g << 3));
  f32x4 ag[8];
  zero8(ag);
#pragma unroll
  for (int nt = 0; nt < 8; ++nt) {
    ag[nt] = MFMA(az, *(const bf16x8*)&Wrl[(nt * 64 + lane) << 3], ag[nt]);
    if (WS) ag[nt] = MFMA(az, *(const bf16x8*)&Wrl[4096 + ((nt * 64 + lane) << 3)], ag[nt]);
  }
  f32x4 am[8];
  zero8(am);
  if (WS) st_issue<4>(sreg, Wm + 16384, tid);
  pass_glob<4, 8>(am, af, Wb[0], lane);
  if (WS) {
    st_commit<4>(sreg, Wb[1], tid);
    __syncthreads();
    pass_glob<4, 8>(am, af, Wb[1], lane);
  }
  bf16_t* op = out + (size_t)(grow0 + g * 4) * 128 + rc;
#pragma unroll
  for (int nt = 0; nt < 8; ++nt)
#pragma unroll
    for (int r = 0; r < 4; ++r)
      op[(size_t)r * 128 + nt * 16] = (bf16_t)(siluf(am[nt][r]) * ag[nt][r]);
}

// ---- E-rows GEMM+silu: A(E x 128) @ W(128 x 64); weights in LDS ----
template <typename TA, bool WS>
__global__ __launch_bounds__(512, 2) void k_gemmE2(const int* __restrict__ flag, int want,
    const TA* __restrict__ A, const bf16_t* __restrict__ W, bf16_t* __restrict__ out, int M) {
  GUARD
  __shared__ __align__(16) bf16_t Wb[2][8192];
  const int tid = threadIdx.x;
  const int lane = tid & 63, wid = tid >> 6;
  const int grow0 = blockIdx.x * 128 + wid * 16;
  const int rc = lane & 15, g = lane >> 4;
  StReg<2> sreg;
  st_issue<2>(sreg, W, tid);
  st_commit<2>(sreg, Wb[0], tid);
  __syncthreads();
  bf16x8 af[4];
#pragma unroll
  for (int ks = 0; ks < 4; ++ks)
    af[ks] = ld8(A + (size_t)(grow0 + rc) * 128 + ks * 32 + (g << 3));
  f32x4 acc[4];
  zero4(acc);
  if (WS) st_issue<2>(sreg, W + 8192, tid);
  pass_glob<4, 4>(acc, af, Wb[0], lane);
  if (WS) {
    st_commit<2>(sreg, Wb[1], tid);
    __syncthreads();
    pass_glob<4, 4>(acc, af, Wb[1], lane);
  }
  bf16_t* op = out + (size_t)(grow0 + g * 4) * 64 + rc;
#pragma unroll
  for (int nt = 0; nt < 4; ++nt)
#pragma unroll
    for (int r = 0; r < 4; ++r) op[(size_t)r * 64 + nt * 16] = (bf16_t)siluf(acc[nt][r]);
}

// ---- N-rows GEMM+silu: A(N x 128, f32) @ W(128 x 128); partial-block safe ----
template <bool WS>
__global__ __launch_bounds__(512, 2) void k_gemmN2(const int* __restrict__ flag, int want,
    const float* __restrict__ A, const bf16_t* __restrict__ W, bf16_t* __restrict__ out, int M) {
  GUARD
  __shared__ __align__(16) bf16_t Wb[2][16384];
  const int tid = threadIdx.x;
  const int lane = tid & 63, wid = tid >> 6;
  const int grow0 = blockIdx.x * 128 + wid * 16;
  const bool act = grow0 < M;
  const int rc = lane & 15, g = lane >> 4;
  StReg<4> sreg;
  st_issue<4>(sreg, W, tid);
  st_commit<4>(sreg, Wb[0], tid);
  __syncthreads();
  bf16x8 af[4];
  if (act) {
#pragma unroll
    for (int ks = 0; ks < 4; ++ks)
      af[ks] = ld8(A + (size_t)(grow0 + rc) * 128 + ks * 32 + (g << 3));
  } else {
#pragma unroll
    for (int ks = 0; ks < 4; ++ks)
#pragma unroll
      for (int j = 0; j < 8; ++j) af[ks][j] = (bf16_t)0.f;
  }
  f32x4 acc[8];
  zero8(acc);
  if (WS) st_issue<4>(sreg, W + 16384, tid);
  pass_glob<4, 8>(acc, af, Wb[0], lane);
  if (WS) {
    st_commit<4>(sreg, Wb[1], tid);
    __syncthreads();
    pass_glob<4, 8>(acc, af, Wb[1], lane);
  }
  if (act) {
    bf16_t* op = out + (size_t)(grow0 + g * 4) * 128 + rc;
#pragma unroll
    for (int nt = 0; nt < 8; ++nt)
#pragma unroll
      for (int r = 0; r < 4; ++r) op[(size_t)r * 128 + nt * 16] = (bf16_t)siluf(acc[nt][r]);
  }
}

// ---- atom embedding scatter ----
template <typename TIN>
__global__ void k_scatter(const int* __restrict__ flag, int want,
                          const bf16_t* __restrict__ m, const TIN* __restrict__ rbf_h,
                          const TIN* __restrict__ Wrbf, const int* __restrict__ idx_t,
                          float* __restrict__ h2) {
  GUARD
  int e = blockIdx.x;
  int c = threadIdx.x;
  float g = 0.f;
#pragma unroll
  for (int k = 0; k < 16; ++k) g += toF(rbf_h[(size_t)e * 16 + k]) * toF(Wrbf[k * 128 + c]);
  atomicAdd(&h2[(size_t)idx_t[e] * 128 + c], (float)m[(size_t)e * 128 + c] * g);
}

// ---- h_new = (h + X)*r2 -> out (TOUT) and X (bf16, for ASI) ----
template <typename TIN, typename TOUT>
__global__ void k_hnew_b(const int* __restrict__ flag, int want,
                         const TIN* __restrict__ h, bf16_t* __restrict__ X,
                         TOUT* __restrict__ out, int n) {
  GUARD
  int i = blockIdx.x * blockDim.x + threadIdx.x;
  if (i >= n) return;
  float v = (toF(h[i]) + (float)X[i]) * INV_SQRT_2;
  X[i] = (bf16_t)v;
  out[i] = fromF<TOUT>(v);
}

// ================================================================================
template <typename TIN, typename TOUT, bool WS>
static void run_pipeline(void* const* d_in, int N, int E, void* d_out,
                         bf16_t* Wpack, bf16_t* s0, bf16_t* s1, bf16_t* s2, bf16_t* s3,
                         float* h2, bf16_t* Rn2, const int* flag, int want, hipStream_t stream) {
  const TIN* h      = (const TIN*)d_in[0];
  const TIN* m_st   = (const TIN*)d_in[1];
  const TIN* rbf_h  = (const TIN*)d_in[2];
  const TIN* rbf3   = (const TIN*)d_in[3];
  const TIN* cbf3   = (const TIN*)d_in[4];
  const TIN* sbf4   = (const TIN*)d_in[5];
  const int* idx_s   = (const int*)d_in[6];
  const int* idx_t   = (const int*)d_in[7];
  const int* idx_sw  = (const int*)d_in[8];
  const int* id3_kt  = (const int*)d_in[9];
  const int* enb_idx = (const int*)d_in[12];
  const TIN* W_skip   = (const TIN*)d_in[16];
  const TIN* Wt_mkt   = (const TIN*)d_in[17];
  const TIN* Wt_rbf   = (const TIN*)d_in[18];
  const TIN* Wt_down  = (const TIN*)d_in[19];
  const TIN* Wt_cbf   = (const TIN*)d_in[20];
  const TIN* Wt_up_st = (const TIN*)d_in[21];
  const TIN* Wt_up_ts = (const TIN*)d_in[22];
  const TIN* Wq_down  = (const TIN*)d_in[23];
  const TIN* Wq_sbf   = (const TIN*)d_in[24];
  const TIN* Wq_up_st = (const TIN*)d_in[25];
  const TIN* Wq_up_ts = (const TIN*)d_in[26];
  const TIN* Wres_before = (const TIN*)d_in[27];
  const TIN* Wres_after  = (const TIN*)d_in[28];
  const TIN* Wres_m      = (const TIN*)d_in[29];
  const TIN* W_ae_rbf    = (const TIN*)d_in[30];
  const TIN* W_ae_dense  = (const TIN*)d_in[31];
  const TIN* W_ae_res    = (const TIN*)d_in[32];
  const TIN* W_asi       = (const TIN*)d_in[33];

  RTable tab;
  int cur = 0, nd = 0;
  auto add = [&](const void* src, int K, int Np, int Kpad, int mode = 0) {
    tab.d[nd].src = src; tab.d[nd].K = K; tab.d[nd].N = Np; tab.d[nd].Kpad = Kpad;
    tab.d[nd].dstoff = cur; tab.d[nd].mode = mode;
    int o = cur;
    cur += 2 * Kpad * Np;  // hi + lo
    ++nd;
    return o;
  };
  const int M128 = 128 * 128;
  int oQd  = add(Wq_down, 128, 64, 128);
  int oMkt = add(Wt_mkt, 128, 128, 128);
  int oRbf = add(Wt_rbf, 16, 128, 32);
  int oTd  = add(Wt_down, 128, 64, 128);
  int oTst = add(Wt_up_st, 64, 128, 64);
  int oTts = add(Wt_up_ts, 64, 128, 64);
  int oQst = add(Wq_up_st, 64, 128, 64);
  int oQts = add(Wq_up_ts, 64, 128, 64);
  int oSk  = add(W_skip, 128, 128, 128);
  int oB0  = add(Wres_before, 128, 128, 128);
  int oB1  = add(Wres_before + M128, 128, 128, 128);
  int oA0  = add(Wres_after, 128, 128, 128);
  int oA1  = add(Wres_after + M128, 128, 128, 128);
  int oA2  = add(Wres_after + 2 * M128, 128, 128, 128);
  int oA3  = add(Wres_after + 3 * M128, 128, 128, 128);
  int oM0  = add(Wres_m, 128, 128, 128);
  int oM1  = add(Wres_m + M128, 128, 128, 128);
  int oAed = add(W_ae_dense, 128, 128, 128);
  int oAe0 = add(W_ae_res, 128, 128, 128);
  int oAe1 = add(W_ae_res + M128, 128, 128, 128);
  int oAe2 = add(W_ae_res + 2 * M128, 128, 128, 128);
  int oAe3 = add(W_ae_res + 3 * M128, 128, 128, 128);
  int oAsi = add(W_asi, 384, 128, 384);
  int oTc  = add(Wt_cbf, 1024, 64, 1024, 1);
  int oQc  = add(Wq_sbf, 1024, 64, 1024, 1);
  (void)cur;

  const int gE = E / 128;  // 625
  const int gN = (N + 127) / 128;
  const int BS = 256;

  bf16_t* mkt_tmp = s0;  // spans s0+s1 (E x 128)
  bf16_t* m_kt = s2;
  bf16_t* m_d  = s3;
  bf16_t* xt = s0;
  bf16_t* xq = s1;
  bf16_t* X  = s2;       // spans s2+s3 (E x 128)
  bf16_t* R2 = s0;       // spans s0+s1 (E x 128)

  k_repack<TIN><<<dim3(256, 25), BS, 0, stream>>>(flag, want, tab, Wpack);

  k_mkt2<TIN, WS><<<gE, 512, 0, stream>>>(flag, want, m_st, rbf3, Wpack + oMkt, Wpack + oRbf,
                                          mkt_tmp, E);
  k_gemmE2<bf16_t, WS><<<gE, 512, 0, stream>>>(flag, want, mkt_tmp, Wpack + oTd, m_kt, E);
  k_gemmE2<TIN, WS><<<gE, 512, 0, stream>>>(flag, want, m_st, Wpack + oQd, m_d, E);
  k_bil_mf<TIN, WS><<<E / 16, BS, 0, stream>>>(flag, want, cbf3, m_kt, id3_kt, Wpack + oTc, xt);
  k_bil_mf<TIN, WS><<<E / 16, BS, 0, stream>>>(flag, want, sbf4, m_d, enb_idx, Wpack + oQc, xq);
  k_comb2<TIN, WS><<<gE, 512, 0, stream>>>(flag, want, m_st, xt, xq, idx_sw,
      Wpack + oSk, Wpack + oTst, Wpack + oTts, Wpack + oQst, Wpack + oQts, X, E);
  k_resE2<TIN, WS><<<gE, 512, 0, stream>>>(flag, want, X, m_st, Wpack + oB0, Wpack + oB1,
      Wpack + oA0, Wpack + oA1, Wpack + oA2, Wpack + oA3, R2, E);
  k_zero<<<(N * 128 + BS - 1) / BS, BS, 0, stream>>>(h2, N * 128);
  k_scatter<TIN><<<E, 128, 0, stream>>>(flag, want, R2, rbf_h, W_ae_rbf, idx_t, h2);
  k_gemmN2<WS><<<gN, 512, 0, stream>>>(flag, want, h2, Wpack + oAed, Rn2, N);
  k_resN2<WS><<<gN, 512, 0, stream>>>(flag, want, Rn2, Wpack + oAe0, Wpack + oAe1,
                                      Wpack + oAe2, Wpack + oAe3, N);
  TOUT* out_h = (TOUT*)d_out;
  TOUT* out_m = out_h + (size_t)N * 128;
  k_hnew_b<TIN, TOUT><<<(N * 128 + BS - 1) / BS, BS, 0, stream>>>(flag, want, h, Rn2, out_h,
                                                                  N * 128);
  k_asi2<TIN, TOUT, WS><<<gE, 512, 0, stream>>>(flag, want, Rn2, R2, idx_s, idx_t,
      Wpack + oAsi, Wpack + oM0, Wpack + oM1, out_m, E);
}

extern "C" void kernel_launch(void* const* d_in, const int* in_sizes, int n_in,
                              void* d_out, int out_size, void* d_ws, size_t ws_size,
                              hipStream_t stream) {
  const int D = 128;
  const int N = in_sizes[0] / D;   // 8000
  const int E = in_sizes[1] / D;   // 80000

  // workspace: Wpack (1,916,928 B) + 32KB staging-overread pad | flag | 4 slots E*64 bf16
  char* base = (char*)d_ws;
  bf16_t* Wpack = (bf16_t*)base;
  int* flag = (int*)(base + 1916928 + 32768);
  char* dyn = base + 1916928 + 32768 + 256;
  size_t U = (size_t)E * 64 * sizeof(bf16_t);
  bf16_t* s0 = (bf16_t*)dyn;
  bf16_t* s1 = (bf16_t*)(dyn + U);
  bf16_t* s2 = (bf16_t*)(dyn + 2 * U);
  bf16_t* s3 = (bf16_t*)(dyn + 3 * U);
  float* h2 = (float*)(dyn + 2 * U);                              // reuses X region (dead by then)
  bf16_t* Rn2 = (bf16_t*)((char*)h2 + (size_t)N * 128 * sizeof(float));

  k_detect<<<1, 64, 0, stream>>>((const unsigned short*)d_in[2], flag);

  run_pipeline<bf16_t, bf16_t, false>(d_in, N, E, d_out, Wpack, s0, s1, s2, s3, h2, Rn2, flag, 0,
                                      stream);
  run_pipeline<float, float, true>(d_in, N, E, d_out, Wpack, s0, s1, s2, s3, h2, Rn2, flag, 1,
                                   stream);
}